// Round 1
// 581.910 us; speedup vs baseline: 1.0054x; 1.0054x over previous
//
#include <hip/hip_runtime.h>
#include <hip/hip_fp16.h>
#include <cmath>

#define TOKENS 2048
#define DMODEL 2048
#define DHID   5632
#define NEXP   8
#define RANK   16
#define LALPHA 2.0f

typedef __attribute__((ext_vector_type(4))) float f32x4;
typedef __attribute__((ext_vector_type(8))) short s16x8;
typedef __attribute__((ext_vector_type(4))) short s16x4;
typedef __attribute__((ext_vector_type(8))) _Float16 f16x8;

__device__ __forceinline__ short f2bf(float f){
  unsigned u = __float_as_uint(f);
  u += 0x7fffu + ((u >> 16) & 1u);
  return (short)(u >> 16);
}
__device__ __forceinline__ short f2h(float f){
  return (short)__half_as_ushort(__float2half(f));
}

// ---------- BK=32 async staging of a 128x32 tile (kept for k_rd) ----------
struct Stage { const short* s0; const short* s1; short* d0; short* d1; };

__device__ __forceinline__ Stage mk_stage(const short* g, long ld, short* t, int tid){
  Stage st;
  const int L0 = tid,      r0 = L0>>2, c0 = ((L0&3) - (r0>>1)) & 3;
  const int L1 = 256+tid,  r1 = L1>>2, c1 = ((L1&3) - (r1>>1)) & 3;
  st.s0 = g + (long)r0*ld + c0*8;  st.d0 = t + L0*8;
  st.s1 = g + (long)r1*ld + c1*8;  st.d1 = t + L1*8;
  return st;
}
__device__ __forceinline__ void do_stage(const Stage& st, int k0){
  __builtin_amdgcn_global_load_lds((const __attribute__((address_space(1))) void*)(st.s0 + k0),
                                   (__attribute__((address_space(3))) void*)st.d0, 16, 0, 0);
  __builtin_amdgcn_global_load_lds((const __attribute__((address_space(1))) void*)(st.s1 + k0),
                                   (__attribute__((address_space(3))) void*)st.d1, 16, 0, 0);
}
__device__ __forceinline__ s16x8 fragb(const short* t, int row, int quad){
  const int p = (quad + (row>>1)) & 3;
  return *(const s16x8*)(t + (row*4 + p)*8);
}

// ---------- BK=64 async staging of a 128x64 tile (16KB) ----------
// Slot L (16B): row r=L>>3, phys chunk p=L&7.  Logical chunk c stored at
// p=(c+(r&7))&7 -> 16 lanes at a fixed c hit 8 distinct chunk positions
// (2-way aliasing only, free).  Source is pre-inverse-swizzled (rule #21).
struct Stage64 { const short* g; short* t; int off[4]; int dof; };

__device__ __forceinline__ Stage64 mk_stage64(const short* g, long ld, short* t, int tid){
  Stage64 st; st.g = g; st.t = t;
  #pragma unroll
  for(int p=0;p<4;p++){
    const int L = p*256 + tid;
    const int r = L>>3, cp = L&7;
    const int c = (cp - (r&7)) & 7;
    st.off[p] = r*(int)ld + c*8;
  }
  st.dof = tid*8;
  return st;
}
__device__ __forceinline__ void do_stage64(const Stage64& st, int k0){
  #pragma unroll
  for(int p=0;p<4;p++)
    __builtin_amdgcn_global_load_lds(
      (const __attribute__((address_space(1))) void*)(st.g + st.off[p] + k0),
      (__attribute__((address_space(3))) void*)(st.t + st.dof + p*2048), 16, 0, 0);
}
__device__ __forceinline__ s16x8 fragb64(const short* t, int row, int ksub, int quad){
  const int c = ksub*4 + quad;
  const int p = (c + (row&7)) & 7;
  return *(const s16x8*)(t + (row*8 + p)*8);
}
__device__ __forceinline__ f16x8 fragh64(const short* t, int row, int ksub, int quad){
  const int c = ksub*4 + quad;
  const int p = (c + (row&7)) & 7;
  return *(const f16x8*)(t + (row*8 + p)*8);
}

// ---------------- K0: cast/gather all GEMM operands ----------------
__global__ void k_cast(const float* __restrict__ x, const float* __restrict__ w_up,
                       const float* __restrict__ w_gate, const float* __restrict__ w_down,
                       const float* __restrict__ upA, const float* __restrict__ gateA,
                       const float* __restrict__ downA, const float* __restrict__ upB,
                       const float* __restrict__ gateB, const float* __restrict__ downB,
                       short* __restrict__ xb, short* __restrict__ wub, short* __restrict__ wgb,
                       short* __restrict__ wdb, short* __restrict__ daA, short* __restrict__ acat,
                       short* __restrict__ upBcat, short* __restrict__ gateBcat, short* __restrict__ wdbcat){
  const long e0 = 4194304, e1 = 15728640, e2 = 27262976, e3 = 38797312;
  const long e4 = 39518208, e5 = 40042496, e6 = 40763392, e7 = 41484288, e8 = 41746432;
  const long i = ((long)blockIdx.x*256 + threadIdx.x) * 4;
  if(i >= e8) return;
  const float* src; short* dst; long l; int fp16 = 0;
  if(i < e0){ src = x; dst = xb; l = i; }
  else if(i < e1){ src = w_up; dst = wub; l = i - e0; }
  else if(i < e2){ src = w_gate; dst = wgb; l = i - e1; }
  else if(i < e3){ src = w_down; dst = wdb; l = i - e2; }
  else if(i < e4){ src = downA; dst = daA; l = i - e3; }   // daA[c][h] == downA flat
  else if(i < e5){ // acat[c][d] = (pj?gateA:upA)[e][r][d], c = e*32+pj*16+r
    l = i - e4;
    const long c = l>>11;
    const long e = c>>5, pj = (c>>4)&1, r = c&15;
    src = (pj ? gateA : upA) + ((e*RANK + r)<<11) + (l&2047) - l;
    dst = acat;
  }
  else if(i < e6){ // upBcat[h][e*16+r] = upB[e][h][r]  (f16)
    l = i - e5;
    const long h = l>>7, c = l&127, e = c>>4, r = c&15;
    src = upB + ((e*DHID + h)*RANK + r) - l;
    dst = upBcat; fp16 = 1;
  }
  else if(i < e7){ // gateBcat
    l = i - e6;
    const long h = l>>7, c = l&127, e = c>>4, r = c&15;
    src = gateB + ((e*DHID + h)*RANK + r) - l;
    dst = gateBcat; fp16 = 1;
  }
  else { // wdbcat[d][e*16+r] = downB[e][d][r]  (f16)
    l = i - e7;
    const long d = l>>7, c = l&127, e = c>>4, r = c&15;
    src = downB + ((e*DMODEL + d)*RANK + r) - l;
    dst = wdbcat; fp16 = 1;
  }
  const float4 v = *(const float4*)(src + l);
  s16x4 o;
  if(fp16){ o[0]=f2h(v.x); o[1]=f2h(v.y); o[2]=f2h(v.z); o[3]=f2h(v.w); }
  else    { o[0]=f2bf(v.x); o[1]=f2bf(v.y); o[2]=f2bf(v.z); o[3]=f2bf(v.w); }
  *(s16x4*)(dst + l) = o;
}

// ---------------- K1: router logits (fp32, one wave per token) + top-2 ----------------
__global__ void k_router(const float* __restrict__ x, const float* __restrict__ gw,
                         int* __restrict__ sel, float* __restrict__ topv){
  const int t = blockIdx.x*4 + (threadIdx.x>>6);
  const int lane = threadIdx.x & 63;
  const float* xr = x + (long)t * DMODEL;
  float acc[NEXP];
  #pragma unroll
  for(int e=0;e<NEXP;e++) acc[e]=0.f;
  #pragma unroll
  for(int it=0; it<8; it++){
    const int d = it*256 + lane*4;
    const float4 xv = *(const float4*)(xr + d);
    #pragma unroll
    for(int e=0;e<NEXP;e++){
      const float4 wv = *(const float4*)(gw + e*DMODEL + d);
      acc[e] += xv.x*wv.x + xv.y*wv.y + xv.z*wv.z + xv.w*wv.w;
    }
  }
  #pragma unroll
  for(int e=0;e<NEXP;e++){
    #pragma unroll
    for(int off=32; off; off>>=1) acc[e] += __shfl_down(acc[e], off, 64);
  }
  if(lane==0){
    int i0=0;
    #pragma unroll
    for(int e=1;e<NEXP;e++) if(acc[e]>acc[i0]) i0=e;
    int i1=-1;
    #pragma unroll
    for(int e=0;e<NEXP;e++){ if(e==i0) continue; if(i1<0 || acc[e]>acc[i1]) i1=e; }
    sel[t*2+0]=i0; sel[t*2+1]=i1;
    topv[t*2+0]=acc[i0]; topv[t*2+1]=acc[i1];
  }
}

// ---------------- K2: softmax over the SEQUENCE axis (faithful) ----------------
__global__ void k_softmax(const float* __restrict__ topv, float* __restrict__ cw){
  const int b = blockIdx.x >> 1, k = blockIdx.x & 1;
  const int base = b*1024;
  __shared__ float red[256];
  float v[4];
  float mx = -1e30f;
  #pragma unroll
  for(int i=0;i<4;i++){
    int s = threadIdx.x + i*256;
    v[i] = topv[(base+s)*2 + k];
    mx = fmaxf(mx, v[i]);
  }
  red[threadIdx.x]=mx; __syncthreads();
  for(int o=128;o;o>>=1){ if(threadIdx.x<o) red[threadIdx.x]=fmaxf(red[threadIdx.x],red[threadIdx.x+o]); __syncthreads(); }
  mx = red[0]; __syncthreads();
  float sum=0.f;
  #pragma unroll
  for(int i=0;i<4;i++){ v[i]=__expf(v[i]-mx); sum+=v[i]; }
  red[threadIdx.x]=sum; __syncthreads();
  for(int o=128;o;o>>=1){ if(threadIdx.x<o) red[threadIdx.x]+=red[threadIdx.x+o]; __syncthreads(); }
  const float inv = 1.f/red[0];
  #pragma unroll
  for(int i=0;i<4;i++){
    int s = threadIdx.x + i*256;
    cw[(base+s)*2+k] = v[i]*inv;
  }
}

// ---------------- K3: Rall += X @ Acat^T (split-K=8, BK=64, atomics) ----------------
__global__ __launch_bounds__(256,2) void k_rank(
    const short* __restrict__ xb, const short* __restrict__ acat, float* __restrict__ Rall){
  __shared__ __align__(16) short At[8192];
  __shared__ __align__(16) short Bt[8192];
  const int c0 = blockIdx.x*128, t0 = blockIdx.y*128;
  const int kbeg = blockIdx.z*256;
  const int tid = threadIdx.x, lane = tid&63, wave = tid>>6;
  const int wm=(wave>>1)*64, wn=(wave&1)*64, fr=lane&15, quad=lane>>4;
  f32x4 acc[4][4];
  #pragma unroll
  for(int i=0;i<4;i++)
    #pragma unroll
    for(int j=0;j<4;j++) acc[i][j]=(f32x4){0.f,0.f,0.f,0.f};
  const Stage64 sA = mk_stage64(xb + (long)t0*DMODEL, DMODEL, At, tid);
  const Stage64 sB = mk_stage64(acat + (long)c0*DMODEL, DMODEL, Bt, tid);
  for(int k0=kbeg; k0<kbeg+256; k0+=64){
    do_stage64(sA, k0); do_stage64(sB, k0);
    __syncthreads();
    #pragma unroll
    for(int s=0;s<2;s++){
      s16x8 af[4];
      #pragma unroll
      for(int i=0;i<4;i++) af[i] = fragb64(At, wm + i*16 + fr, s, quad);
      #pragma unroll
      for(int j=0;j<4;j++){
        const s16x8 bf = fragb64(Bt, wn + j*16 + fr, s, quad);
        #pragma unroll
        for(int i=0;i<4;i++)
          acc[i][j] = __builtin_amdgcn_mfma_f32_16x16x32_bf16(af[i], bf, acc[i][j], 0,0,0);
      }
    }
    __syncthreads();
  }
  #pragma unroll
  for(int i=0;i<4;i++)
    #pragma unroll
    for(int j=0;j<4;j++){
      const int rbase = wm + i*16 + quad*4, col = wn + j*16 + fr;
      #pragma unroll
      for(int reg=0;reg<4;reg++)
        atomicAdd(&Rall[(long)(t0+rbase+reg)*256 + c0 + col], acc[i][j][reg]);
    }
}

// ---------------- K3b: Rsel[k][t][e*16+r] = (e==sel_k) ? alpha*Rall : 0  (f16) ----------------
__global__ void k_rsel(const float* __restrict__ Rall, const int* __restrict__ sel,
                       short* __restrict__ RselU, short* __restrict__ RselG){
  const int idx = blockIdx.x*256 + threadIdx.x;      // [2][TOKENS][128]
  const int c = idx & 127, t = (idx>>7) & (TOKENS-1), k = idx>>18;
  const int e = c>>4, r = c&15;
  const int s = sel[t*2+k];
  const int m = (e==s);
  RselU[idx] = f2h(m ? LALPHA*Rall[(long)t*256 + e*32 + r]      : 0.f);
  RselG[idx] = f2h(m ? LALPHA*Rall[(long)t*256 + e*32 + 16 + r] : 0.f);
}

// ---------------- K3c: LoRA up/gate deltas, written in FRAGMENT ORDER ----------------
// LF layout: per (blin = by*44+bx, tid): 256 halves at
//   [mat(z)*128 + slot*64 + i*16 + j*4 + reg]
// k_main (same grid / wave / lane mapping) reads these back with 16B loads.
__global__ __launch_bounds__(256,2) void k_lora(
    const short* __restrict__ RselU, const short* __restrict__ RselG,
    const short* __restrict__ upBcat, const short* __restrict__ gateBcat,
    short* __restrict__ LF){
  __shared__ __align__(16) short At[8192];   // Rsel slot0 tile
  __shared__ __align__(16) short Gt[8192];   // Rsel slot1 tile
  __shared__ __align__(16) short Bt[8192];   // Bcat tile
  const int h0 = blockIdx.x*128, t0 = blockIdx.y*128;
  const short* Rsel = blockIdx.z ? RselG : RselU;
  const short* Bcat = blockIdx.z ? gateBcat : upBcat;
  const int tid = threadIdx.x, lane = tid&63, wave = tid>>6;
  const int wm=(wave>>1)*64, wn=(wave&1)*64, fr=lane&15, quad=lane>>4;
  f32x4 l0[4][4], l1[4][4];
  #pragma unroll
  for(int i=0;i<4;i++)
    #pragma unroll
    for(int j=0;j<4;j++){ l0[i][j]=(f32x4){0.f,0.f,0.f,0.f}; l1[i][j]=l0[i][j]; }
  const Stage64 sB  = mk_stage64(Bcat + (long)h0*128, 128, Bt, tid);
  const Stage64 sR0 = mk_stage64(Rsel + (long)t0*128, 128, At, tid);
  const Stage64 sR1 = mk_stage64(Rsel + ((long)TOKENS + t0)*128, 128, Gt, tid);
  for(int k0=0; k0<128; k0+=64){
    do_stage64(sB, k0); do_stage64(sR0, k0); do_stage64(sR1, k0);
    __syncthreads();
    #pragma unroll
    for(int s=0;s<2;s++){
      f16x8 a0[4], a1[4];
      #pragma unroll
      for(int i=0;i<4;i++){ a0[i] = fragh64(At, wm + i*16 + fr, s, quad);
                            a1[i] = fragh64(Gt, wm + i*16 + fr, s, quad); }
      #pragma unroll
      for(int j=0;j<4;j++){
        const f16x8 bf = fragh64(Bt, wn + j*16 + fr, s, quad);
        #pragma unroll
        for(int i=0;i<4;i++){
          l0[i][j] = __builtin_amdgcn_mfma_f32_16x16x32_f16(a0[i], bf, l0[i][j], 0,0,0);
          l1[i][j] = __builtin_amdgcn_mfma_f32_16x16x32_f16(a1[i], bf, l1[i][j], 0,0,0);
        }
      }
    }
    __syncthreads();
  }
  short* o = LF + (((long)(blockIdx.y*44 + blockIdx.x)*256 + tid)*256) + blockIdx.z*128;
  #pragma unroll
  for(int i=0;i<4;i++){
    s16x8 p0a, p0b, p1a, p1b;
    #pragma unroll
    for(int r=0;r<4;r++){
      p0a[r]   = f2h(l0[i][0][r]); p0a[4+r] = f2h(l0[i][1][r]);
      p0b[r]   = f2h(l0[i][2][r]); p0b[4+r] = f2h(l0[i][3][r]);
      p1a[r]   = f2h(l1[i][0][r]); p1a[4+r] = f2h(l1[i][1][r]);
      p1b[r]   = f2h(l1[i][2][r]); p1b[4+r] = f2h(l1[i][3][r]);
    }
    *(s16x8*)(o + i*16)          = p0a;
    *(s16x8*)(o + i*16 + 8)      = p0b;
    *(s16x8*)(o + 64 + i*16)     = p1a;
    *(s16x8*)(o + 64 + i*16 + 8) = p1b;
  }
}

// ---------------- K4: base up/gate GEMM (BK=64) + fragment-order LoRA epilogue ----------------
__global__ __launch_bounds__(256,2) void k_main(
    const short* __restrict__ xb, const short* __restrict__ wub, const short* __restrict__ wgb,
    const short* __restrict__ LF,
    const float* __restrict__ cw, unsigned short* __restrict__ ch, unsigned short* __restrict__ chsum){
  __shared__ __align__(16) short At[8192];
  __shared__ __align__(16) short Ut[8192];
  __shared__ __align__(16) short Gt[8192];
  __shared__ float cwv[128][2];
  const int h0 = blockIdx.x*128, t0 = blockIdx.y*128;
  const int tid = threadIdx.x, lane = tid&63, wave = tid>>6;
  const int wm=(wave>>1)*64, wn=(wave&1)*64, fr=lane&15, quad=lane>>4;
  { const int tl = tid>>1, k = tid&1; cwv[tl][k] = cw[(t0+tl)*2 + k]; }
  f32x4 au[4][4], ag[4][4];
  #pragma unroll
  for(int i=0;i<4;i++)
    #pragma unroll
    for(int j=0;j<4;j++){ au[i][j]=(f32x4){0.f,0.f,0.f,0.f}; ag[i][j]=au[i][j]; }
  const Stage64 sA = mk_stage64(xb + (long)t0*DMODEL, DMODEL, At, tid);
  const Stage64 sU = mk_stage64(wub + (long)h0*DMODEL, DMODEL, Ut, tid);
  const Stage64 sG = mk_stage64(wgb + (long)h0*DMODEL, DMODEL, Gt, tid);
  for(int k0=0; k0<DMODEL; k0+=64){
    do_stage64(sA, k0); do_stage64(sU, k0); do_stage64(sG, k0);
    __syncthreads();
    #pragma unroll
    for(int s=0;s<2;s++){
      s16x8 af[4];
      #pragma unroll
      for(int i=0;i<4;i++) af[i] = fragb64(At, wm + i*16 + fr, s, quad);
      #pragma unroll
      for(int j=0;j<4;j++){
        const s16x8 bu = fragb64(Ut, wn + j*16 + fr, s, quad);
        const s16x8 bg = fragb64(Gt, wn + j*16 + fr, s, quad);
        #pragma unroll
        for(int i=0;i<4;i++){
          au[i][j] = __builtin_amdgcn_mfma_f32_16x16x32_bf16(af[i], bu, au[i][j], 0,0,0);
          ag[i][j] = __builtin_amdgcn_mfma_f32_16x16x32_bf16(af[i], bg, ag[i][j], 0,0,0);
        }
      }
    }
    __syncthreads();
  }
  // ---- epilogue: fragment-order LoRA loads (16B), silu*gate, scale, 3 streams ----
  const short* Lf = LF + (((long)(blockIdx.y*44 + blockIdx.x)*256 + tid)*256);
  #pragma unroll
  for(int i=0;i<4;i++){
    f16x8 Uv0[2], Uv1[2], Gv0[2], Gv1[2];
    Uv0[0] = *(const f16x8*)(Lf + i*16);        Uv0[1] = *(const f16x8*)(Lf + i*16 + 8);
    Uv1[0] = *(const f16x8*)(Lf + 64 + i*16);   Uv1[1] = *(const f16x8*)(Lf + 64 + i*16 + 8);
    Gv0[0] = *(const f16x8*)(Lf + 128 + i*16);  Gv0[1] = *(const f16x8*)(Lf + 128 + i*16 + 8);
    Gv1[0] = *(const f16x8*)(Lf + 192 + i*16);  Gv1[1] = *(const f16x8*)(Lf + 192 + i*16 + 8);
    #pragma unroll
    for(int reg=0;reg<4;reg++){
      const int tl = wm + i*16 + quad*4 + reg;
      const float c0 = cwv[tl][0], c1 = cwv[tl][1];
      const long row0 = (long)(t0+tl)*DHID + h0;
      const long row1 = ((long)TOKENS + t0+tl)*DHID + h0;
      unsigned short* r0 = ch + row0;
      unsigned short* r1 = ch + row1;
      unsigned short* rs = chsum + row0;
      #pragma unroll
      for(int j=0;j<4;j++){
        const int hl = wn + j*16 + fr;
        const int q = (j&1)*4 + reg, hv = j>>1;
        const float u0 = au[i][j][reg] + (float)Uv0[hv][q];
        const float g0 = ag[i][j][reg] + (float)Gv0[hv][q];
        const float h0v = (u0 / (1.f + __expf(-u0))) * g0;
        const float u1 = au[i][j][reg] + (float)Uv1[hv][q];
        const float g1 = ag[i][j][reg] + (float)Gv1[hv][q];
        const float h1v = (u1 / (1.f + __expf(-u1))) * g1;
        const float v0 = c0*h0v, v1 = c1*h1v;
        r0[hl] = (unsigned short)f2bf(v0);
        r1[hl] = (unsigned short)f2bf(v1);
        rs[hl] = (unsigned short)f2bf(v0+v1);
      }
    }
  }
}

// ---------------- K5: RD[t][k][c] = ch_k @ daA^T (ksplit=16, atomics, BK=32) ----------------
__global__ __launch_bounds__(256,4) void k_rd(
    const unsigned short* __restrict__ ch, const short* __restrict__ daA,
    float* __restrict__ RD){
  __shared__ __align__(16) short At[4096];
  __shared__ __align__(16) short Bt[4096];
  const int slot = blockIdx.x>>4, ks = blockIdx.x&15;
  const int t0 = blockIdx.y*128;
  const int tid = threadIdx.x, lane = tid&63, wave = tid>>6;
  const int wm=(wave>>1)*64, wn=(wave&1)*64, fr=lane&15, quad=lane>>4;
  f32x4 acc[4][4];
  #pragma unroll
  for(int i=0;i<4;i++)
    #pragma unroll
    for(int j=0;j<4;j++) acc[i][j]=(f32x4){0.f,0.f,0.f,0.f};
  const Stage sA = mk_stage((const short*)ch + ((long)slot*TOKENS + t0)*DHID, DHID, At, tid);
  const Stage sB = mk_stage(daA, DHID, Bt, tid);
  const int kbeg = ks*352;
  for(int kk=0; kk<352; kk+=32){
    do_stage(sA, kbeg+kk); do_stage(sB, kbeg+kk);
    __syncthreads();
    s16x8 af[4];
    #pragma unroll
    for(int i=0;i<4;i++) af[i] = fragb(At, wm + i*16 + fr, quad);
    #pragma unroll
    for(int j=0;j<4;j++){
      const s16x8 bf = fragb(Bt, wn + j*16 + fr, quad);
      #pragma unroll
      for(int i=0;i<4;i++)
        acc[i][j] = __builtin_amdgcn_mfma_f32_16x16x32_bf16(af[i], bf, acc[i][j], 0,0,0);
    }
    __syncthreads();
  }
  #pragma unroll
  for(int i=0;i<4;i++)
    #pragma unroll
    for(int j=0;j<4;j++){
      const int rbase = wm + i*16 + quad*4, col = wn + j*16 + fr;
      #pragma unroll
      for(int reg=0;reg<4;reg++)
        atomicAdd(&RD[((long)(t0+rbase+reg)*2 + slot)*128 + col], acc[i][j][reg]);
    }
}

// ---------------- K5b: RDhat[t][c] (f16) = alpha * RD at selected expert blocks ----------------
__global__ void k_scatter(const float* __restrict__ RD, const int* __restrict__ sel,
                          __half* __restrict__ RDhat){
  const int idx = blockIdx.x*256 + threadIdx.x;   // over T*128
  const int t = idx>>7, c = idx&127, e = c>>4;
  const int s0 = sel[t*2], s1 = sel[t*2+1];
  float v = 0.f;
  if(e == s0) v = LALPHA * RD[((long)t*2+0)*128 + c];
  else if(e == s1) v = LALPHA * RD[((long)t*2+1)*128 + c];
  RDhat[idx] = __float2half(v);
}

// ---------------- K6: out += chsum @ wdb^T (split-K=2, BK=64) + RDhat @ wdbcat^T ----------------
__global__ __launch_bounds__(256,2) void k_down(
    const unsigned short* __restrict__ chsum, const short* __restrict__ wdb,
    const short* __restrict__ RDhat, const short* __restrict__ wdbcat,
    float* __restrict__ out){
  __shared__ __align__(16) short At[8192];
  __shared__ __align__(16) short Bt[8192];
  const int d0 = blockIdx.x*128, t0 = blockIdx.y*128, ks = blockIdx.z;
  const int tid = threadIdx.x, lane = tid&63, wave = tid>>6;
  const int wm=(wave>>1)*64, wn=(wave&1)*64, fr=lane&15, quad=lane>>4;
  f32x4 acc[4][4];
  #pragma unroll
  for(int i=0;i<4;i++)
    #pragma unroll
    for(int j=0;j<4;j++) acc[i][j]=(f32x4){0.f,0.f,0.f,0.f};
  const Stage64 sA = mk_stage64((const short*)chsum + (long)t0*DHID, DHID, At, tid);
  const Stage64 sB = mk_stage64(wdb + (long)d0*DHID, DHID, Bt, tid);
  const int kbeg = ks*2816;
  for(int kk=0; kk<2816; kk+=64){
    do_stage64(sA, kbeg+kk); do_stage64(sB, kbeg+kk);
    __syncthreads();
    #pragma unroll
    for(int s=0;s<2;s++){
      s16x8 af[4];
      #pragma unroll
      for(int i=0;i<4;i++) af[i] = fragb64(At, wm + i*16 + fr, s, quad);
      #pragma unroll
      for(int j=0;j<4;j++){
        const s16x8 bf = fragb64(Bt, wn + j*16 + fr, s, quad);
        #pragma unroll
        for(int i=0;i<4;i++)
          acc[i][j] = __builtin_amdgcn_mfma_f32_16x16x32_bf16(af[i], bf, acc[i][j], 0,0,0);
      }
    }
    __syncthreads();
  }
  if(ks == 0){
    // LoRA-down phase: K=128 over RDhat (f16) @ wdbcat (f16)
    const Stage64 sAh = mk_stage64(RDhat + (long)t0*128, 128, At, tid);
    const Stage64 sBh = mk_stage64(wdbcat + (long)d0*128, 128, Bt, tid);
    for(int k0=0; k0<128; k0+=64){
      do_stage64(sAh, k0); do_stage64(sBh, k0);
      __syncthreads();
      #pragma unroll
      for(int s=0;s<2;s++){
        f16x8 af[4];
        #pragma unroll
        for(int i=0;i<4;i++) af[i] = fragh64(At, wm + i*16 + fr, s, quad);
        #pragma unroll
        for(int j=0;j<4;j++){
          const f16x8 bf = fragh64(Bt, wn + j*16 + fr, s, quad);
          #pragma unroll
          for(int i=0;i<4;i++)
            acc[i][j] = __builtin_amdgcn_mfma_f32_16x16x32_f16(af[i], bf, acc[i][j], 0,0,0);
        }
      }
      __syncthreads();
    }
  }
  #pragma unroll
  for(int i=0;i<4;i++)
    #pragma unroll
    for(int j=0;j<4;j++){
      const int rbase = wm + i*16 + quad*4, col = wn + j*16 + fr;
      #pragma unroll
      for(int reg=0;reg<4;reg++)
        atomicAdd(&out[(long)(t0+rbase+reg)*DMODEL + d0 + col], acc[i][j][reg]);
    }
}

extern "C" void kernel_launch(void* const* d_in, const int* in_sizes, int n_in,
                              void* d_out, int out_size, void* d_ws, size_t ws_size,
                              hipStream_t stream){
  (void)in_sizes; (void)n_in; (void)out_size; (void)ws_size;
  const float* x      = (const float*)d_in[0];
  const float* gate_w = (const float*)d_in[1];
  const float* w_up   = (const float*)d_in[2];
  const float* w_gate = (const float*)d_in[3];
  const float* w_down = (const float*)d_in[4];
  const float* up_A   = (const float*)d_in[5];
  const float* up_B   = (const float*)d_in[6];
  const float* gate_A = (const float*)d_in[7];
  const float* gate_B = (const float*)d_in[8];
  const float* down_A = (const float*)d_in[9];
  const float* down_B = (const float*)d_in[10];
  float* out = (float*)d_out;

  char* ws = (char*)d_ws;
  size_t off = 0;
  auto alloc = [&](size_t bytes){ void* p = ws + off; off += (bytes + 255) & ~(size_t)255; return p; };
  short* xb       = (short*)alloc((size_t)TOKENS*DMODEL*2);
  short* wub      = (short*)alloc((size_t)DHID*DMODEL*2);
  short* wgb      = (short*)alloc((size_t)DHID*DMODEL*2);
  short* wdb      = (short*)alloc((size_t)DMODEL*DHID*2);
  short* daA      = (short*)alloc((size_t)128*DHID*2);
  short* acat     = (short*)alloc((size_t)256*DMODEL*2);
  short* upBcat   = (short*)alloc((size_t)DHID*128*2);
  short* gateBcat = (short*)alloc((size_t)DHID*128*2);
  short* wdbcat   = (short*)alloc((size_t)DMODEL*128*2);
  unsigned short* ch    = (unsigned short*)alloc((size_t)2*TOKENS*DHID*2);
  unsigned short* chsum = (unsigned short*)alloc((size_t)TOKENS*DHID*2);
  short* LF     = (short*)alloc((size_t)704*256*256*2);   // fragment-order LoRA deltas
  float* Rall   = (float*)alloc((size_t)TOKENS*256*4);
  short* RselU  = (short*)alloc((size_t)2*TOKENS*128*2);
  short* RselG  = (short*)alloc((size_t)2*TOKENS*128*2);
  float* RD     = (float*)alloc((size_t)TOKENS*2*128*4);
  __half* RDhat = (__half*)alloc((size_t)TOKENS*128*2);
  int*   sel    = (int*)alloc((size_t)TOKENS*2*4);
  float* topv   = (float*)alloc((size_t)TOKENS*2*4);
  float* cw     = (float*)alloc((size_t)TOKENS*2*4);

  (void)hipMemsetAsync(RD, 0, (size_t)TOKENS*2*128*4, stream);
  (void)hipMemsetAsync(Rall, 0, (size_t)TOKENS*256*4, stream);
  (void)hipMemsetAsync(out, 0, (size_t)TOKENS*DMODEL*4, stream);
  k_cast<<<40768, 256, 0, stream>>>(x, w_up, w_gate, w_down, up_A, gate_A, down_A,
                                    up_B, gate_B, down_B,
                                    xb, wub, wgb, wdb, daA, acat, upBcat, gateBcat, wdbcat);
  k_router<<<512, 256, 0, stream>>>(x, gate_w, sel, topv);
  k_softmax<<<4, 256, 0, stream>>>(topv, cw);
  k_rank<<<dim3(2,16,8), 256, 0, stream>>>(xb, acat, Rall);
  k_rsel<<<2048, 256, 0, stream>>>(Rall, sel, RselU, RselG);
  k_lora<<<dim3(44,16,2), 256, 0, stream>>>(RselU, RselG, upBcat, gateBcat, LF);
  k_main<<<dim3(44,16), 256, 0, stream>>>(xb, wub, wgb, LF, cw, ch, chsum);
  k_rd<<<dim3(32,16), 256, 0, stream>>>(ch, daA, RD);
  k_scatter<<<1024, 256, 0, stream>>>(RD, sel, RDhat);
  k_down<<<dim3(16,16,2), 256, 0, stream>>>(chsum, wdb, (const short*)RDhat, wdbcat, out);
}

// Round 2
// 538.857 us; speedup vs baseline: 1.0858x; 1.0799x over previous
//
#include <hip/hip_runtime.h>
#include <hip/hip_fp16.h>
#include <cmath>

#define TOKENS 2048
#define DMODEL 2048
#define DHID   5632
#define NEXP   8
#define RANK   16
#define LALPHA 2.0f

typedef __attribute__((ext_vector_type(4))) float f32x4;
typedef __attribute__((ext_vector_type(8))) short s16x8;
typedef __attribute__((ext_vector_type(4))) short s16x4;
typedef __attribute__((ext_vector_type(8))) _Float16 f16x8;

__device__ __forceinline__ short f2bf(float f){
  unsigned u = __float_as_uint(f);
  u += 0x7fffu + ((u >> 16) & 1u);
  return (short)(u >> 16);
}
__device__ __forceinline__ short f2h(float f){
  return (short)__half_as_ushort(__float2half(f));
}

// ---------- BK=32 staging of a 128x32 tile (8KB), dest selectable (dbuf) ----------
// LDS tile = 512 slots of 16B, linear. slot L: row r=L>>2, phys chunk p=L&3.
// Logical k-chunk c stored at p=(c+(r>>1))&3 => 2-way-only bank aliasing (free).
struct Src2 { const short* s0; const short* s1; };

__device__ __forceinline__ Src2 mk_src(const short* g, long ld, int tid){
  Src2 st;
  const int L0 = tid,      r0 = L0>>2, c0 = ((L0&3) - (r0>>1)) & 3;
  const int L1 = 256+tid,  r1 = L1>>2, c1 = ((L1&3) - (r1>>1)) & 3;
  st.s0 = g + (long)r0*ld + c0*8;
  st.s1 = g + (long)r1*ld + c1*8;
  return st;
}
__device__ __forceinline__ void stage2(const Src2& st, int k0, short* t, int tid){
  __builtin_amdgcn_global_load_lds((const __attribute__((address_space(1))) void*)(st.s0 + k0),
                                   (__attribute__((address_space(3))) void*)(t + tid*8), 16, 0, 0);
  __builtin_amdgcn_global_load_lds((const __attribute__((address_space(1))) void*)(st.s1 + k0),
                                   (__attribute__((address_space(3))) void*)(t + (256+tid)*8), 16, 0, 0);
}
__device__ __forceinline__ s16x8 fragb(const short* t, int row, int quad){
  const int p = (quad + (row>>1)) & 3;
  return *(const s16x8*)(t + (row*4 + p)*8);
}
__device__ __forceinline__ f16x8 fragh(const short* t, int row, int quad){
  const int p = (quad + (row>>1)) & 3;
  return *(const f16x8*)(t + (row*4 + p)*8);
}

// ---------- BK=64 staging of a 128x64 tile (16KB) — used by k_rank / k_lora ----------
struct Stage64 { const short* g; short* t; int off[4]; int dof; };

__device__ __forceinline__ Stage64 mk_stage64(const short* g, long ld, short* t, int tid){
  Stage64 st; st.g = g; st.t = t;
  #pragma unroll
  for(int p=0;p<4;p++){
    const int L = p*256 + tid;
    const int r = L>>3, cp = L&7;
    const int c = (cp - (r&7)) & 7;
    st.off[p] = r*(int)ld + c*8;
  }
  st.dof = tid*8;
  return st;
}
__device__ __forceinline__ void do_stage64(const Stage64& st, int k0){
  #pragma unroll
  for(int p=0;p<4;p++)
    __builtin_amdgcn_global_load_lds(
      (const __attribute__((address_space(1))) void*)(st.g + st.off[p] + k0),
      (__attribute__((address_space(3))) void*)(st.t + st.dof + p*2048), 16, 0, 0);
}
__device__ __forceinline__ s16x8 fragb64(const short* t, int row, int ksub, int quad){
  const int c = ksub*4 + quad;
  const int p = (c + (row&7)) & 7;
  return *(const s16x8*)(t + (row*8 + p)*8);
}
__device__ __forceinline__ f16x8 fragh64(const short* t, int row, int ksub, int quad){
  const int c = ksub*4 + quad;
  const int p = (c + (row&7)) & 7;
  return *(const f16x8*)(t + (row*8 + p)*8);
}

// ---------------- K0: cast/gather all GEMM operands ----------------
__global__ void k_cast(const float* __restrict__ x, const float* __restrict__ w_up,
                       const float* __restrict__ w_gate, const float* __restrict__ w_down,
                       const float* __restrict__ upA, const float* __restrict__ gateA,
                       const float* __restrict__ downA, const float* __restrict__ upB,
                       const float* __restrict__ gateB, const float* __restrict__ downB,
                       short* __restrict__ xb, short* __restrict__ wub, short* __restrict__ wgb,
                       short* __restrict__ wdb, short* __restrict__ daA, short* __restrict__ acat,
                       short* __restrict__ upBcat, short* __restrict__ gateBcat, short* __restrict__ wdbcat){
  const long e0 = 4194304, e1 = 15728640, e2 = 27262976, e3 = 38797312;
  const long e4 = 39518208, e5 = 40042496, e6 = 40763392, e7 = 41484288, e8 = 41746432;
  const long i = ((long)blockIdx.x*256 + threadIdx.x) * 4;
  if(i >= e8) return;
  const float* src; short* dst; long l; int fp16 = 0;
  if(i < e0){ src = x; dst = xb; l = i; }
  else if(i < e1){ src = w_up; dst = wub; l = i - e0; }
  else if(i < e2){ src = w_gate; dst = wgb; l = i - e1; }
  else if(i < e3){ src = w_down; dst = wdb; l = i - e2; }
  else if(i < e4){ src = downA; dst = daA; l = i - e3; }   // daA[c][h] == downA flat
  else if(i < e5){ // acat[c][d] = (pj?gateA:upA)[e][r][d], c = e*32+pj*16+r
    l = i - e4;
    const long c = l>>11;
    const long e = c>>5, pj = (c>>4)&1, r = c&15;
    src = (pj ? gateA : upA) + ((e*RANK + r)<<11) + (l&2047) - l;
    dst = acat;
  }
  else if(i < e6){ // upBcat[h][e*16+r] = upB[e][h][r]  (f16)
    l = i - e5;
    const long h = l>>7, c = l&127, e = c>>4, r = c&15;
    src = upB + ((e*DHID + h)*RANK + r) - l;
    dst = upBcat; fp16 = 1;
  }
  else if(i < e7){ // gateBcat
    l = i - e6;
    const long h = l>>7, c = l&127, e = c>>4, r = c&15;
    src = gateB + ((e*DHID + h)*RANK + r) - l;
    dst = gateBcat; fp16 = 1;
  }
  else { // wdbcat[d][e*16+r] = downB[e][d][r]  (f16)
    l = i - e7;
    const long d = l>>7, c = l&127, e = c>>4, r = c&15;
    src = downB + ((e*DMODEL + d)*RANK + r) - l;
    dst = wdbcat; fp16 = 1;
  }
  const float4 v = *(const float4*)(src + l);
  s16x4 o;
  if(fp16){ o[0]=f2h(v.x); o[1]=f2h(v.y); o[2]=f2h(v.z); o[3]=f2h(v.w); }
  else    { o[0]=f2bf(v.x); o[1]=f2bf(v.y); o[2]=f2bf(v.z); o[3]=f2bf(v.w); }
  *(s16x4*)(dst + l) = o;
}

// ---------------- K1: router logits (fp32, one wave per token) + top-2 ----------------
__global__ void k_router(const float* __restrict__ x, const float* __restrict__ gw,
                         int* __restrict__ sel, float* __restrict__ topv){
  const int t = blockIdx.x*4 + (threadIdx.x>>6);
  const int lane = threadIdx.x & 63;
  const float* xr = x + (long)t * DMODEL;
  float acc[NEXP];
  #pragma unroll
  for(int e=0;e<NEXP;e++) acc[e]=0.f;
  #pragma unroll
  for(int it=0; it<8; it++){
    const int d = it*256 + lane*4;
    const float4 xv = *(const float4*)(xr + d);
    #pragma unroll
    for(int e=0;e<NEXP;e++){
      const float4 wv = *(const float4*)(gw + e*DMODEL + d);
      acc[e] += xv.x*wv.x + xv.y*wv.y + xv.z*wv.z + xv.w*wv.w;
    }
  }
  #pragma unroll
  for(int e=0;e<NEXP;e++){
    #pragma unroll
    for(int off=32; off; off>>=1) acc[e] += __shfl_down(acc[e], off, 64);
  }
  if(lane==0){
    int i0=0;
    #pragma unroll
    for(int e=1;e<NEXP;e++) if(acc[e]>acc[i0]) i0=e;
    int i1=-1;
    #pragma unroll
    for(int e=0;e<NEXP;e++){ if(e==i0) continue; if(i1<0 || acc[e]>acc[i1]) i1=e; }
    sel[t*2+0]=i0; sel[t*2+1]=i1;
    topv[t*2+0]=acc[i0]; topv[t*2+1]=acc[i1];
  }
}

// ---------------- K2: softmax over the SEQUENCE axis (faithful) ----------------
__global__ void k_softmax(const float* __restrict__ topv, float* __restrict__ cw){
  const int b = blockIdx.x >> 1, k = blockIdx.x & 1;
  const int base = b*1024;
  __shared__ float red[256];
  float v[4];
  float mx = -1e30f;
  #pragma unroll
  for(int i=0;i<4;i++){
    int s = threadIdx.x + i*256;
    v[i] = topv[(base+s)*2 + k];
    mx = fmaxf(mx, v[i]);
  }
  red[threadIdx.x]=mx; __syncthreads();
  for(int o=128;o;o>>=1){ if(threadIdx.x<o) red[threadIdx.x]=fmaxf(red[threadIdx.x],red[threadIdx.x+o]); __syncthreads(); }
  mx = red[0]; __syncthreads();
  float sum=0.f;
  #pragma unroll
  for(int i=0;i<4;i++){ v[i]=__expf(v[i]-mx); sum+=v[i]; }
  red[threadIdx.x]=sum; __syncthreads();
  for(int o=128;o;o>>=1){ if(threadIdx.x<o) red[threadIdx.x]+=red[threadIdx.x+o]; __syncthreads(); }
  const float inv = 1.f/red[0];
  #pragma unroll
  for(int i=0;i<4;i++){
    int s = threadIdx.x + i*256;
    cw[(base+s)*2+k] = v[i]*inv;
  }
}

// ---------------- K3: Rall += X @ Acat^T (split-K=8, BK=64, atomics) ----------------
__global__ __launch_bounds__(256,2) void k_rank(
    const short* __restrict__ xb, const short* __restrict__ acat, float* __restrict__ Rall){
  __shared__ __align__(16) short At[8192];
  __shared__ __align__(16) short Bt[8192];
  const int c0 = blockIdx.x*128, t0 = blockIdx.y*128;
  const int kbeg = blockIdx.z*256;
  const int tid = threadIdx.x, lane = tid&63, wave = tid>>6;
  const int wm=(wave>>1)*64, wn=(wave&1)*64, fr=lane&15, quad=lane>>4;
  f32x4 acc[4][4];
  #pragma unroll
  for(int i=0;i<4;i++)
    #pragma unroll
    for(int j=0;j<4;j++) acc[i][j]=(f32x4){0.f,0.f,0.f,0.f};
  const Stage64 sA = mk_stage64(xb + (long)t0*DMODEL, DMODEL, At, tid);
  const Stage64 sB = mk_stage64(acat + (long)c0*DMODEL, DMODEL, Bt, tid);
  for(int k0=kbeg; k0<kbeg+256; k0+=64){
    do_stage64(sA, k0); do_stage64(sB, k0);
    __syncthreads();
    #pragma unroll
    for(int s=0;s<2;s++){
      s16x8 af[4];
      #pragma unroll
      for(int i=0;i<4;i++) af[i] = fragb64(At, wm + i*16 + fr, s, quad);
      #pragma unroll
      for(int j=0;j<4;j++){
        const s16x8 bf = fragb64(Bt, wn + j*16 + fr, s, quad);
        #pragma unroll
        for(int i=0;i<4;i++)
          acc[i][j] = __builtin_amdgcn_mfma_f32_16x16x32_bf16(af[i], bf, acc[i][j], 0,0,0);
      }
    }
    __syncthreads();
  }
  #pragma unroll
  for(int i=0;i<4;i++)
    #pragma unroll
    for(int j=0;j<4;j++){
      const int rbase = wm + i*16 + quad*4, col = wn + j*16 + fr;
      #pragma unroll
      for(int reg=0;reg<4;reg++)
        atomicAdd(&Rall[(long)(t0+rbase+reg)*256 + c0 + col], acc[i][j][reg]);
    }
}

// ---------------- K3b: Rsel[k][t][e*16+r] = (e==sel_k) ? alpha*Rall : 0  (f16) ----------------
__global__ void k_rsel(const float* __restrict__ Rall, const int* __restrict__ sel,
                       short* __restrict__ RselU, short* __restrict__ RselG){
  const int idx = blockIdx.x*256 + threadIdx.x;      // [2][TOKENS][128]
  const int c = idx & 127, t = (idx>>7) & (TOKENS-1), k = idx>>18;
  const int e = c>>4, r = c&15;
  const int s = sel[t*2+k];
  const int m = (e==s);
  RselU[idx] = f2h(m ? LALPHA*Rall[(long)t*256 + e*32 + r]      : 0.f);
  RselG[idx] = f2h(m ? LALPHA*Rall[(long)t*256 + e*32 + 16 + r] : 0.f);
}

// ---------------- K3c: LoRA up/gate deltas, FRAGMENT ORDER, chunk-major (coalesced) ----------------
// LF layout: per block blin = by*44+bx: 32 chunks q of [256 threads][8 halves].
//   q = mat(z)*16 + slot*8 + i*2 + h ;  addr = blin*65536 + (q*256 + tid)*8
// Every 16B store/load is wave-contiguous (1KB per wave instruction).
__global__ __launch_bounds__(256,2) void k_lora(
    const short* __restrict__ RselU, const short* __restrict__ RselG,
    const short* __restrict__ upBcat, const short* __restrict__ gateBcat,
    short* __restrict__ LF){
  __shared__ __align__(16) short At[8192];   // Rsel slot0 tile
  __shared__ __align__(16) short Gt[8192];   // Rsel slot1 tile
  __shared__ __align__(16) short Bt[8192];   // Bcat tile
  const int h0 = blockIdx.x*128, t0 = blockIdx.y*128;
  const short* Rsel = blockIdx.z ? RselG : RselU;
  const short* Bcat = blockIdx.z ? gateBcat : upBcat;
  const int tid = threadIdx.x, lane = tid&63, wave = tid>>6;
  const int wm=(wave>>1)*64, wn=(wave&1)*64, fr=lane&15, quad=lane>>4;
  f32x4 l0[4][4], l1[4][4];
  #pragma unroll
  for(int i=0;i<4;i++)
    #pragma unroll
    for(int j=0;j<4;j++){ l0[i][j]=(f32x4){0.f,0.f,0.f,0.f}; l1[i][j]=l0[i][j]; }
  const Stage64 sB  = mk_stage64(Bcat + (long)h0*128, 128, Bt, tid);
  const Stage64 sR0 = mk_stage64(Rsel + (long)t0*128, 128, At, tid);
  const Stage64 sR1 = mk_stage64(Rsel + ((long)TOKENS + t0)*128, 128, Gt, tid);
  for(int k0=0; k0<128; k0+=64){
    do_stage64(sB, k0); do_stage64(sR0, k0); do_stage64(sR1, k0);
    __syncthreads();
    #pragma unroll
    for(int s=0;s<2;s++){
      f16x8 a0[4], a1[4];
      #pragma unroll
      for(int i=0;i<4;i++){ a0[i] = fragh64(At, wm + i*16 + fr, s, quad);
                            a1[i] = fragh64(Gt, wm + i*16 + fr, s, quad); }
      #pragma unroll
      for(int j=0;j<4;j++){
        const f16x8 bf = fragh64(Bt, wn + j*16 + fr, s, quad);
        #pragma unroll
        for(int i=0;i<4;i++){
          l0[i][j] = __builtin_amdgcn_mfma_f32_16x16x32_f16(a0[i], bf, l0[i][j], 0,0,0);
          l1[i][j] = __builtin_amdgcn_mfma_f32_16x16x32_f16(a1[i], bf, l1[i][j], 0,0,0);
        }
      }
    }
    __syncthreads();
  }
  // chunk-major output: base for this mat's 16 chunks
  short* o = LF + (long)(blockIdx.y*44 + blockIdx.x)*65536 + ((long)blockIdx.z*16*256 + tid)*8;
  #pragma unroll
  for(int i=0;i<4;i++){
    s16x8 p0a, p0b, p1a, p1b;
    #pragma unroll
    for(int r=0;r<4;r++){
      p0a[r]   = f2h(l0[i][0][r]); p0a[4+r] = f2h(l0[i][1][r]);
      p0b[r]   = f2h(l0[i][2][r]); p0b[4+r] = f2h(l0[i][3][r]);
      p1a[r]   = f2h(l1[i][0][r]); p1a[4+r] = f2h(l1[i][1][r]);
      p1b[r]   = f2h(l1[i][2][r]); p1b[4+r] = f2h(l1[i][3][r]);
    }
    *(s16x8*)(o + (i*2+0)*2048)     = p0a;   // q = z*16 + 0*8 + i*2 + 0
    *(s16x8*)(o + (i*2+1)*2048)     = p0b;   // q = z*16 + 0*8 + i*2 + 1
    *(s16x8*)(o + (8 + i*2+0)*2048) = p1a;   // q = z*16 + 1*8 + i*2 + 0
    *(s16x8*)(o + (8 + i*2+1)*2048) = p1b;   // q = z*16 + 1*8 + i*2 + 1
  }
}

// ---------------- K4: base up/gate GEMM (BK=32, double-buffered) + LoRA epilogue ----------------
__global__ __launch_bounds__(256,2) void k_main(
    const short* __restrict__ xb, const short* __restrict__ wub, const short* __restrict__ wgb,
    const short* __restrict__ LF,
    const float* __restrict__ cw, unsigned short* __restrict__ ch, unsigned short* __restrict__ chsum){
  __shared__ __align__(16) short At[2][4096];
  __shared__ __align__(16) short Ut[2][4096];
  __shared__ __align__(16) short Gt[2][4096];
  __shared__ float cwv[128][2];
  const int h0 = blockIdx.x*128, t0 = blockIdx.y*128;
  const int tid = threadIdx.x, lane = tid&63, wave = tid>>6;
  const int wm=(wave>>1)*64, wn=(wave&1)*64, fr=lane&15, quad=lane>>4;
  { const int tl = tid>>1, k = tid&1; cwv[tl][k] = cw[(t0+tl)*2 + k]; }
  f32x4 au[4][4], ag[4][4];
  #pragma unroll
  for(int i=0;i<4;i++)
    #pragma unroll
    for(int j=0;j<4;j++){ au[i][j]=(f32x4){0.f,0.f,0.f,0.f}; ag[i][j]=au[i][j]; }
  const Src2 sA = mk_src(xb + (long)t0*DMODEL, DMODEL, tid);
  const Src2 sU = mk_src(wub + (long)h0*DMODEL, DMODEL, tid);
  const Src2 sG = mk_src(wgb + (long)h0*DMODEL, DMODEL, tid);
  // prologue: stage tile 0 into buf 0
  stage2(sA, 0, At[0], tid); stage2(sU, 0, Ut[0], tid); stage2(sG, 0, Gt[0], tid);
  __syncthreads();                     // implicit vmcnt(0) drains prologue stage
  int cur = 0;
  for(int k0=0; k0<DMODEL; k0+=32){
    const int nxt = cur^1;
    if(k0+32 < DMODEL){               // prefetch next tile BEFORE compute (T3 minimum 2-phase)
      stage2(sA, k0+32, At[nxt], tid);
      stage2(sU, k0+32, Ut[nxt], tid);
      stage2(sG, k0+32, Gt[nxt], tid);
    }
    __builtin_amdgcn_sched_barrier(0); // keep prefetch issue above the compute phase
    s16x8 af[4];
    #pragma unroll
    for(int i=0;i<4;i++) af[i] = fragb(At[cur], wm + i*16 + fr, quad);
    #pragma unroll
    for(int j=0;j<4;j++){
      const s16x8 bu = fragb(Ut[cur], wn + j*16 + fr, quad);
      const s16x8 bg = fragb(Gt[cur], wn + j*16 + fr, quad);
      #pragma unroll
      for(int i=0;i<4;i++){
        au[i][j] = __builtin_amdgcn_mfma_f32_16x16x32_bf16(af[i], bu, au[i][j], 0,0,0);
        ag[i][j] = __builtin_amdgcn_mfma_f32_16x16x32_bf16(af[i], bg, ag[i][j], 0,0,0);
      }
    }
    __syncthreads();                  // single barrier/step: waits prefetch + guards overwrite
    cur = nxt;
  }
  // ---- epilogue: chunk-major LoRA loads (coalesced 16B), silu*gate, scale, 3 streams ----
  const short* Lf = LF + (long)(blockIdx.y*44 + blockIdx.x)*65536 + (long)tid*8;
  #pragma unroll
  for(int i=0;i<4;i++){
    f16x8 Uv0[2], Uv1[2], Gv0[2], Gv1[2];
    Uv0[0] = *(const f16x8*)(Lf + (i*2+0)*2048);       Uv0[1] = *(const f16x8*)(Lf + (i*2+1)*2048);
    Uv1[0] = *(const f16x8*)(Lf + (8+i*2+0)*2048);     Uv1[1] = *(const f16x8*)(Lf + (8+i*2+1)*2048);
    Gv0[0] = *(const f16x8*)(Lf + (16+i*2+0)*2048);    Gv0[1] = *(const f16x8*)(Lf + (16+i*2+1)*2048);
    Gv1[0] = *(const f16x8*)(Lf + (24+i*2+0)*2048);    Gv1[1] = *(const f16x8*)(Lf + (24+i*2+1)*2048);
    #pragma unroll
    for(int reg=0;reg<4;reg++){
      const int tl = wm + i*16 + quad*4 + reg;
      const float c0 = cwv[tl][0], c1 = cwv[tl][1];
      const long row0 = (long)(t0+tl)*DHID + h0;
      const long row1 = ((long)TOKENS + t0+tl)*DHID + h0;
      unsigned short* r0 = ch + row0;
      unsigned short* r1 = ch + row1;
      unsigned short* rs = chsum + row0;
      #pragma unroll
      for(int j=0;j<4;j++){
        const int hl = wn + j*16 + fr;
        const int q = (j&1)*4 + reg, hv = j>>1;
        const float u0 = au[i][j][reg] + (float)Uv0[hv][q];
        const float g0 = ag[i][j][reg] + (float)Gv0[hv][q];
        const float h0v = (u0 / (1.f + __expf(-u0))) * g0;
        const float u1 = au[i][j][reg] + (float)Uv1[hv][q];
        const float g1 = ag[i][j][reg] + (float)Gv1[hv][q];
        const float h1v = (u1 / (1.f + __expf(-u1))) * g1;
        const float v0 = c0*h0v, v1 = c1*h1v;
        r0[hl] = (unsigned short)f2bf(v0);
        r1[hl] = (unsigned short)f2bf(v1);
        rs[hl] = (unsigned short)f2bf(v0+v1);
      }
    }
  }
}

// ---------------- K5: RD[t][k][c] = ch_k @ daA^T (ksplit=16, atomics, BK=32) ----------------
__global__ __launch_bounds__(256,4) void k_rd(
    const unsigned short* __restrict__ ch, const short* __restrict__ daA,
    float* __restrict__ RD){
  __shared__ __align__(16) short At[4096];
  __shared__ __align__(16) short Bt[4096];
  const int slot = blockIdx.x>>4, ks = blockIdx.x&15;
  const int t0 = blockIdx.y*128;
  const int tid = threadIdx.x, lane = tid&63, wave = tid>>6;
  const int wm=(wave>>1)*64, wn=(wave&1)*64, fr=lane&15, quad=lane>>4;
  f32x4 acc[4][4];
  #pragma unroll
  for(int i=0;i<4;i++)
    #pragma unroll
    for(int j=0;j<4;j++) acc[i][j]=(f32x4){0.f,0.f,0.f,0.f};
  const Src2 sA = mk_src((const short*)ch + ((long)slot*TOKENS + t0)*DHID, DHID, tid);
  const Src2 sB = mk_src(daA, DHID, tid);
  const int kbeg = ks*352;
  for(int kk=0; kk<352; kk+=32){
    stage2(sA, kbeg+kk, At, tid); stage2(sB, kbeg+kk, Bt, tid);
    __syncthreads();
    s16x8 af[4];
    #pragma unroll
    for(int i=0;i<4;i++) af[i] = fragb(At, wm + i*16 + fr, quad);
    #pragma unroll
    for(int j=0;j<4;j++){
      const s16x8 bf = fragb(Bt, wn + j*16 + fr, quad);
      #pragma unroll
      for(int i=0;i<4;i++)
        acc[i][j] = __builtin_amdgcn_mfma_f32_16x16x32_bf16(af[i], bf, acc[i][j], 0,0,0);
    }
    __syncthreads();
  }
  #pragma unroll
  for(int i=0;i<4;i++)
    #pragma unroll
    for(int j=0;j<4;j++){
      const int rbase = wm + i*16 + quad*4, col = wn + j*16 + fr;
      #pragma unroll
      for(int reg=0;reg<4;reg++)
        atomicAdd(&RD[((long)(t0+rbase+reg)*2 + slot)*128 + col], acc[i][j][reg]);
    }
}

// ---------------- K5b: RDhat[t][c] (f16) = alpha * RD at selected expert blocks ----------------
__global__ void k_scatter(const float* __restrict__ RD, const int* __restrict__ sel,
                          __half* __restrict__ RDhat){
  const int idx = blockIdx.x*256 + threadIdx.x;   // over T*128
  const int t = idx>>7, c = idx&127, e = c>>4;
  const int s0 = sel[t*2], s1 = sel[t*2+1];
  float v = 0.f;
  if(e == s0) v = LALPHA * RD[((long)t*2+0)*128 + c];
  else if(e == s1) v = LALPHA * RD[((long)t*2+1)*128 + c];
  RDhat[idx] = __float2half(v);
}

// ---------------- K6: out += chsum @ wdb^T (split-K=2, BK=32 dbuf) + RDhat @ wdbcat^T ----------------
__global__ __launch_bounds__(256,2) void k_down(
    const unsigned short* __restrict__ chsum, const short* __restrict__ wdb,
    const short* __restrict__ RDhat, const short* __restrict__ wdbcat,
    float* __restrict__ out){
  __shared__ __align__(16) short At[2][4096];
  __shared__ __align__(16) short Bt[2][4096];
  const int d0 = blockIdx.x*128, t0 = blockIdx.y*128, ks = blockIdx.z;
  const int tid = threadIdx.x, lane = tid&63, wave = tid>>6;
  const int wm=(wave>>1)*64, wn=(wave&1)*64, fr=lane&15, quad=lane>>4;
  f32x4 acc[4][4];
  #pragma unroll
  for(int i=0;i<4;i++)
    #pragma unroll
    for(int j=0;j<4;j++) acc[i][j]=(f32x4){0.f,0.f,0.f,0.f};
  const Src2 sA = mk_src((const short*)chsum + (long)t0*DHID, DHID, tid);
  const Src2 sB = mk_src(wdb + (long)d0*DHID, DHID, tid);
  const int kbeg = ks*2816;
  stage2(sA, kbeg, At[0], tid); stage2(sB, kbeg, Bt[0], tid);
  __syncthreads();
  int cur = 0;
  for(int kk=0; kk<2816; kk+=32){
    const int nxt = cur^1;
    if(kk+32 < 2816){
      stage2(sA, kbeg+kk+32, At[nxt], tid);
      stage2(sB, kbeg+kk+32, Bt[nxt], tid);
    }
    __builtin_amdgcn_sched_barrier(0);
    s16x8 af[4];
    #pragma unroll
    for(int i=0;i<4;i++) af[i] = fragb(At[cur], wm + i*16 + fr, quad);
    #pragma unroll
    for(int j=0;j<4;j++){
      const s16x8 bf = fragb(Bt[cur], wn + j*16 + fr, quad);
      #pragma unroll
      for(int i=0;i<4;i++)
        acc[i][j] = __builtin_amdgcn_mfma_f32_16x16x32_bf16(af[i], bf, acc[i][j], 0,0,0);
    }
    __syncthreads();
    cur = nxt;
  }
  if(ks == 0){
    // LoRA-down phase: K=128 over RDhat (f16) @ wdbcat (f16), double-buffered
    const Src2 sAh = mk_src(RDhat + (long)t0*128, 128, tid);
    const Src2 sBh = mk_src(wdbcat + (long)d0*128, 128, tid);
    stage2(sAh, 0, At[cur], tid); stage2(sBh, 0, Bt[cur], tid);
    __syncthreads();
    for(int k0=0; k0<128; k0+=32){
      const int nxt = cur^1;
      if(k0+32 < 128){
        stage2(sAh, k0+32, At[nxt], tid);
        stage2(sBh, k0+32, Bt[nxt], tid);
      }
      __builtin_amdgcn_sched_barrier(0);
      f16x8 af[4];
      #pragma unroll
      for(int i=0;i<4;i++) af[i] = fragh(At[cur], wm + i*16 + fr, quad);
      #pragma unroll
      for(int j=0;j<4;j++){
        const f16x8 bf = fragh(Bt[cur], wn + j*16 + fr, quad);
        #pragma unroll
        for(int i=0;i<4;i++)
          acc[i][j] = __builtin_amdgcn_mfma_f32_16x16x32_f16(af[i], bf, acc[i][j], 0,0,0);
      }
      __syncthreads();
      cur = nxt;
    }
  }
  #pragma unroll
  for(int i=0;i<4;i++)
    #pragma unroll
    for(int j=0;j<4;j++){
      const int rbase = wm + i*16 + quad*4, col = wn + j*16 + fr;
      #pragma unroll
      for(int reg=0;reg<4;reg++)
        atomicAdd(&out[(long)(t0+rbase+reg)*DMODEL + d0 + col], acc[i][j][reg]);
    }
}

extern "C" void kernel_launch(void* const* d_in, const int* in_sizes, int n_in,
                              void* d_out, int out_size, void* d_ws, size_t ws_size,
                              hipStream_t stream){
  (void)in_sizes; (void)n_in; (void)out_size; (void)ws_size;
  const float* x      = (const float*)d_in[0];
  const float* gate_w = (const float*)d_in[1];
  const float* w_up   = (const float*)d_in[2];
  const float* w_gate = (const float*)d_in[3];
  const float* w_down = (const float*)d_in[4];
  const float* up_A   = (const float*)d_in[5];
  const float* up_B   = (const float*)d_in[6];
  const float* gate_A = (const float*)d_in[7];
  const float* gate_B = (const float*)d_in[8];
  const float* down_A = (const float*)d_in[9];
  const float* down_B = (const float*)d_in[10];
  float* out = (float*)d_out;

  char* ws = (char*)d_ws;
  size_t off = 0;
  auto alloc = [&](size_t bytes){ void* p = ws + off; off += (bytes + 255) & ~(size_t)255; return p; };
  short* xb       = (short*)alloc((size_t)TOKENS*DMODEL*2);
  short* wub      = (short*)alloc((size_t)DHID*DMODEL*2);
  short* wgb      = (short*)alloc((size_t)DHID*DMODEL*2);
  short* wdb      = (short*)alloc((size_t)DMODEL*DHID*2);
  short* daA      = (short*)alloc((size_t)128*DHID*2);
  short* acat     = (short*)alloc((size_t)256*DMODEL*2);
  short* upBcat   = (short*)alloc((size_t)DHID*128*2);
  short* gateBcat = (short*)alloc((size_t)DHID*128*2);
  short* wdbcat   = (short*)alloc((size_t)DMODEL*128*2);
  unsigned short* ch    = (unsigned short*)alloc((size_t)2*TOKENS*DHID*2);
  unsigned short* chsum = (unsigned short*)alloc((size_t)TOKENS*DHID*2);
  short* LF     = (short*)alloc((size_t)704*65536*2);   // chunk-major fragment LoRA deltas
  float* Rall   = (float*)alloc((size_t)TOKENS*256*4);
  short* RselU  = (short*)alloc((size_t)2*TOKENS*128*2);
  short* RselG  = (short*)alloc((size_t)2*TOKENS*128*2);
  float* RD     = (float*)alloc((size_t)TOKENS*2*128*4);
  __half* RDhat = (__half*)alloc((size_t)TOKENS*128*2);
  int*   sel    = (int*)alloc((size_t)TOKENS*2*4);
  float* topv   = (float*)alloc((size_t)TOKENS*2*4);
  float* cw     = (float*)alloc((size_t)TOKENS*2*4);

  (void)hipMemsetAsync(RD, 0, (size_t)TOKENS*2*128*4, stream);
  (void)hipMemsetAsync(Rall, 0, (size_t)TOKENS*256*4, stream);
  (void)hipMemsetAsync(out, 0, (size_t)TOKENS*DMODEL*4, stream);
  k_cast<<<40768, 256, 0, stream>>>(x, w_up, w_gate, w_down, up_A, gate_A, down_A,
                                    up_B, gate_B, down_B,
                                    xb, wub, wgb, wdb, daA, acat, upBcat, gateBcat, wdbcat);
  k_router<<<512, 256, 0, stream>>>(x, gate_w, sel, topv);
  k_softmax<<<4, 256, 0, stream>>>(topv, cw);
  k_rank<<<dim3(2,16,8), 256, 0, stream>>>(xb, acat, Rall);
  k_rsel<<<2048, 256, 0, stream>>>(Rall, sel, RselU, RselG);
  k_lora<<<dim3(44,16,2), 256, 0, stream>>>(RselU, RselG, upBcat, gateBcat, LF);
  k_main<<<dim3(44,16), 256, 0, stream>>>(xb, wub, wgb, LF, cw, ch, chsum);
  k_rd<<<dim3(32,16), 256, 0, stream>>>(ch, daA, RD);
  k_scatter<<<1024, 256, 0, stream>>>(RD, sel, RDhat);
  k_down<<<dim3(16,16,2), 256, 0, stream>>>(chsum, wdb, (const short*)RDhat, wdbcat, out);
}

// Round 3
// 537.936 us; speedup vs baseline: 1.0876x; 1.0017x over previous
//
#include <hip/hip_runtime.h>
#include <hip/hip_fp16.h>
#include <cmath>

#define TOKENS 2048
#define DMODEL 2048
#define DHID   5632
#define NEXP   8
#define RANK   16
#define LALPHA 2.0f

typedef __attribute__((ext_vector_type(4))) float f32x4;
typedef __attribute__((ext_vector_type(8))) short s16x8;
typedef __attribute__((ext_vector_type(4))) short s16x4;
typedef __attribute__((ext_vector_type(8))) _Float16 f16x8;

__device__ __forceinline__ short f2bf(float f){
  unsigned u = __float_as_uint(f);
  u += 0x7fffu + ((u >> 16) & 1u);
  return (short)(u >> 16);
}
__device__ __forceinline__ short f2h(float f){
  return (short)__half_as_ushort(__float2half(f));
}

// ---------- BK=32 staging of a 128x32 tile (8KB), dest selectable (multi-buffer) ----------
// LDS tile = 512 slots of 16B, linear. slot L: row r=L>>2, phys chunk p=L&3.
// Logical k-chunk c stored at p=(c+(r>>1))&3 => 2-way-only bank aliasing (free).
struct Src2 { const short* s0; const short* s1; };

__device__ __forceinline__ Src2 mk_src(const short* g, long ld, int tid){
  Src2 st;
  const int L0 = tid,      r0 = L0>>2, c0 = ((L0&3) - (r0>>1)) & 3;
  const int L1 = 256+tid,  r1 = L1>>2, c1 = ((L1&3) - (r1>>1)) & 3;
  st.s0 = g + (long)r0*ld + c0*8;
  st.s1 = g + (long)r1*ld + c1*8;
  return st;
}
__device__ __forceinline__ void stage2(const Src2& st, int k0, short* t, int tid){
  __builtin_amdgcn_global_load_lds((const __attribute__((address_space(1))) void*)(st.s0 + k0),
                                   (__attribute__((address_space(3))) void*)(t + tid*8), 16, 0, 0);
  __builtin_amdgcn_global_load_lds((const __attribute__((address_space(1))) void*)(st.s1 + k0),
                                   (__attribute__((address_space(3))) void*)(t + (256+tid)*8), 16, 0, 0);
}
__device__ __forceinline__ s16x8 fragb(const short* t, int row, int quad){
  const int p = (quad + (row>>1)) & 3;
  return *(const s16x8*)(t + (row*4 + p)*8);
}
__device__ __forceinline__ f16x8 fragh(const short* t, int row, int quad){
  const int p = (quad + (row>>1)) & 3;
  return *(const f16x8*)(t + (row*4 + p)*8);
}

// ---------- BK=64 staging of a 128x64 tile (16KB) — used by k_rank / k_lora ----------
struct Stage64 { const short* g; short* t; int off[4]; int dof; };

__device__ __forceinline__ Stage64 mk_stage64(const short* g, long ld, short* t, int tid){
  Stage64 st; st.g = g; st.t = t;
  #pragma unroll
  for(int p=0;p<4;p++){
    const int L = p*256 + tid;
    const int r = L>>3, cp = L&7;
    const int c = (cp - (r&7)) & 7;
    st.off[p] = r*(int)ld + c*8;
  }
  st.dof = tid*8;
  return st;
}
__device__ __forceinline__ void do_stage64(const Stage64& st, int k0){
  #pragma unroll
  for(int p=0;p<4;p++)
    __builtin_amdgcn_global_load_lds(
      (const __attribute__((address_space(1))) void*)(st.g + st.off[p] + k0),
      (__attribute__((address_space(3))) void*)(st.t + st.dof + p*2048), 16, 0, 0);
}
__device__ __forceinline__ s16x8 fragb64(const short* t, int row, int ksub, int quad){
  const int c = ksub*4 + quad;
  const int p = (c + (row&7)) & 7;
  return *(const s16x8*)(t + (row*8 + p)*8);
}
__device__ __forceinline__ f16x8 fragh64(const short* t, int row, int ksub, int quad){
  const int c = ksub*4 + quad;
  const int p = (c + (row&7)) & 7;
  return *(const f16x8*)(t + (row*8 + p)*8);
}

// ---------------- K0: cast/gather all GEMM operands ----------------
__global__ void k_cast(const float* __restrict__ x, const float* __restrict__ w_up,
                       const float* __restrict__ w_gate, const float* __restrict__ w_down,
                       const float* __restrict__ upA, const float* __restrict__ gateA,
                       const float* __restrict__ downA, const float* __restrict__ upB,
                       const float* __restrict__ gateB, const float* __restrict__ downB,
                       short* __restrict__ xb, short* __restrict__ wub, short* __restrict__ wgb,
                       short* __restrict__ wdb, short* __restrict__ daA, short* __restrict__ acat,
                       short* __restrict__ upBcat, short* __restrict__ gateBcat, short* __restrict__ wdbcat){
  const long e0 = 4194304, e1 = 15728640, e2 = 27262976, e3 = 38797312;
  const long e4 = 39518208, e5 = 40042496, e6 = 40763392, e7 = 41484288, e8 = 41746432;
  const long i = ((long)blockIdx.x*256 + threadIdx.x) * 4;
  if(i >= e8) return;
  const float* src; short* dst; long l; int fp16 = 0;
  if(i < e0){ src = x; dst = xb; l = i; }
  else if(i < e1){ src = w_up; dst = wub; l = i - e0; }
  else if(i < e2){ src = w_gate; dst = wgb; l = i - e1; }
  else if(i < e3){ src = w_down; dst = wdb; l = i - e2; }
  else if(i < e4){ src = downA; dst = daA; l = i - e3; }   // daA[c][h] == downA flat
  else if(i < e5){ // acat[c][d] = (pj?gateA:upA)[e][r][d], c = e*32+pj*16+r
    l = i - e4;
    const long c = l>>11;
    const long e = c>>5, pj = (c>>4)&1, r = c&15;
    src = (pj ? gateA : upA) + ((e*RANK + r)<<11) + (l&2047) - l;
    dst = acat;
  }
  else if(i < e6){ // upBcat[h][e*16+r] = upB[e][h][r]  (f16)
    l = i - e5;
    const long h = l>>7, c = l&127, e = c>>4, r = c&15;
    src = upB + ((e*DHID + h)*RANK + r) - l;
    dst = upBcat; fp16 = 1;
  }
  else if(i < e7){ // gateBcat
    l = i - e6;
    const long h = l>>7, c = l&127, e = c>>4, r = c&15;
    src = gateB + ((e*DHID + h)*RANK + r) - l;
    dst = gateBcat; fp16 = 1;
  }
  else { // wdbcat[d][e*16+r] = downB[e][d][r]  (f16)
    l = i - e7;
    const long d = l>>7, c = l&127, e = c>>4, r = c&15;
    src = downB + ((e*DMODEL + d)*RANK + r) - l;
    dst = wdbcat; fp16 = 1;
  }
  const float4 v = *(const float4*)(src + l);
  s16x4 o;
  if(fp16){ o[0]=f2h(v.x); o[1]=f2h(v.y); o[2]=f2h(v.z); o[3]=f2h(v.w); }
  else    { o[0]=f2bf(v.x); o[1]=f2bf(v.y); o[2]=f2bf(v.z); o[3]=f2bf(v.w); }
  *(s16x4*)(dst + l) = o;
}

// ---------------- K1: router logits (fp32, one wave per token) + top-2 ----------------
__global__ void k_router(const float* __restrict__ x, const float* __restrict__ gw,
                         int* __restrict__ sel, float* __restrict__ topv){
  const int t = blockIdx.x*4 + (threadIdx.x>>6);
  const int lane = threadIdx.x & 63;
  const float* xr = x + (long)t * DMODEL;
  float acc[NEXP];
  #pragma unroll
  for(int e=0;e<NEXP;e++) acc[e]=0.f;
  #pragma unroll
  for(int it=0; it<8; it++){
    const int d = it*256 + lane*4;
    const float4 xv = *(const float4*)(xr + d);
    #pragma unroll
    for(int e=0;e<NEXP;e++){
      const float4 wv = *(const float4*)(gw + e*DMODEL + d);
      acc[e] += xv.x*wv.x + xv.y*wv.y + xv.z*wv.z + xv.w*wv.w;
    }
  }
  #pragma unroll
  for(int e=0;e<NEXP;e++){
    #pragma unroll
    for(int off=32; off; off>>=1) acc[e] += __shfl_down(acc[e], off, 64);
  }
  if(lane==0){
    int i0=0;
    #pragma unroll
    for(int e=1;e<NEXP;e++) if(acc[e]>acc[i0]) i0=e;
    int i1=-1;
    #pragma unroll
    for(int e=0;e<NEXP;e++){ if(e==i0) continue; if(i1<0 || acc[e]>acc[i1]) i1=e; }
    sel[t*2+0]=i0; sel[t*2+1]=i1;
    topv[t*2+0]=acc[i0]; topv[t*2+1]=acc[i1];
  }
}

// ---------------- K2: softmax over the SEQUENCE axis (faithful) ----------------
__global__ void k_softmax(const float* __restrict__ topv, float* __restrict__ cw){
  const int b = blockIdx.x >> 1, k = blockIdx.x & 1;
  const int base = b*1024;
  __shared__ float red[256];
  float v[4];
  float mx = -1e30f;
  #pragma unroll
  for(int i=0;i<4;i++){
    int s = threadIdx.x + i*256;
    v[i] = topv[(base+s)*2 + k];
    mx = fmaxf(mx, v[i]);
  }
  red[threadIdx.x]=mx; __syncthreads();
  for(int o=128;o;o>>=1){ if(threadIdx.x<o) red[threadIdx.x]=fmaxf(red[threadIdx.x],red[threadIdx.x+o]); __syncthreads(); }
  mx = red[0]; __syncthreads();
  float sum=0.f;
  #pragma unroll
  for(int i=0;i<4;i++){ v[i]=__expf(v[i]-mx); sum+=v[i]; }
  red[threadIdx.x]=sum; __syncthreads();
  for(int o=128;o;o>>=1){ if(threadIdx.x<o) red[threadIdx.x]+=red[threadIdx.x+o]; __syncthreads(); }
  const float inv = 1.f/red[0];
  #pragma unroll
  for(int i=0;i<4;i++){
    int s = threadIdx.x + i*256;
    cw[(base+s)*2+k] = v[i]*inv;
  }
}

// ---------------- K3: Rall += X @ Acat^T (split-K=8, BK=64, atomics) ----------------
__global__ __launch_bounds__(256,2) void k_rank(
    const short* __restrict__ xb, const short* __restrict__ acat, float* __restrict__ Rall){
  __shared__ __align__(16) short At[8192];
  __shared__ __align__(16) short Bt[8192];
  const int c0 = blockIdx.x*128, t0 = blockIdx.y*128;
  const int kbeg = blockIdx.z*256;
  const int tid = threadIdx.x, lane = tid&63, wave = tid>>6;
  const int wm=(wave>>1)*64, wn=(wave&1)*64, fr=lane&15, quad=lane>>4;
  f32x4 acc[4][4];
  #pragma unroll
  for(int i=0;i<4;i++)
    #pragma unroll
    for(int j=0;j<4;j++) acc[i][j]=(f32x4){0.f,0.f,0.f,0.f};
  const Stage64 sA = mk_stage64(xb + (long)t0*DMODEL, DMODEL, At, tid);
  const Stage64 sB = mk_stage64(acat + (long)c0*DMODEL, DMODEL, Bt, tid);
  for(int k0=kbeg; k0<kbeg+256; k0+=64){
    do_stage64(sA, k0); do_stage64(sB, k0);
    __syncthreads();
    #pragma unroll
    for(int s=0;s<2;s++){
      s16x8 af[4];
      #pragma unroll
      for(int i=0;i<4;i++) af[i] = fragb64(At, wm + i*16 + fr, s, quad);
      #pragma unroll
      for(int j=0;j<4;j++){
        const s16x8 bf = fragb64(Bt, wn + j*16 + fr, s, quad);
        #pragma unroll
        for(int i=0;i<4;i++)
          acc[i][j] = __builtin_amdgcn_mfma_f32_16x16x32_bf16(af[i], bf, acc[i][j], 0,0,0);
      }
    }
    __syncthreads();
  }
  #pragma unroll
  for(int i=0;i<4;i++)
    #pragma unroll
    for(int j=0;j<4;j++){
      const int rbase = wm + i*16 + quad*4, col = wn + j*16 + fr;
      #pragma unroll
      for(int reg=0;reg<4;reg++)
        atomicAdd(&Rall[(long)(t0+rbase+reg)*256 + c0 + col], acc[i][j][reg]);
    }
}

// ---------------- K3b: Rsel[k][t][e*16+r] = (e==sel_k) ? alpha*Rall : 0  (f16) ----------------
__global__ void k_rsel(const float* __restrict__ Rall, const int* __restrict__ sel,
                       short* __restrict__ RselU, short* __restrict__ RselG){
  const int idx = blockIdx.x*256 + threadIdx.x;      // [2][TOKENS][128]
  const int c = idx & 127, t = (idx>>7) & (TOKENS-1), k = idx>>18;
  const int e = c>>4, r = c&15;
  const int s = sel[t*2+k];
  const int m = (e==s);
  RselU[idx] = f2h(m ? LALPHA*Rall[(long)t*256 + e*32 + r]      : 0.f);
  RselG[idx] = f2h(m ? LALPHA*Rall[(long)t*256 + e*32 + 16 + r] : 0.f);
}

// ---------------- K3c: LoRA up/gate deltas, FRAGMENT ORDER, chunk-major (coalesced) ----------------
// LF layout: per block blin = by*44+bx: 32 chunks q of [256 threads][8 halves].
//   q = mat(z)*16 + slot*8 + i*2 + h ;  addr = blin*65536 + (q*256 + tid)*8
// Every 16B store/load is wave-contiguous (1KB per wave instruction).
__global__ __launch_bounds__(256,2) void k_lora(
    const short* __restrict__ RselU, const short* __restrict__ RselG,
    const short* __restrict__ upBcat, const short* __restrict__ gateBcat,
    short* __restrict__ LF){
  __shared__ __align__(16) short At[8192];   // Rsel slot0 tile
  __shared__ __align__(16) short Gt[8192];   // Rsel slot1 tile
  __shared__ __align__(16) short Bt[8192];   // Bcat tile
  const int h0 = blockIdx.x*128, t0 = blockIdx.y*128;
  const short* Rsel = blockIdx.z ? RselG : RselU;
  const short* Bcat = blockIdx.z ? gateBcat : upBcat;
  const int tid = threadIdx.x, lane = tid&63, wave = tid>>6;
  const int wm=(wave>>1)*64, wn=(wave&1)*64, fr=lane&15, quad=lane>>4;
  f32x4 l0[4][4], l1[4][4];
  #pragma unroll
  for(int i=0;i<4;i++)
    #pragma unroll
    for(int j=0;j<4;j++){ l0[i][j]=(f32x4){0.f,0.f,0.f,0.f}; l1[i][j]=l0[i][j]; }
  const Stage64 sB  = mk_stage64(Bcat + (long)h0*128, 128, Bt, tid);
  const Stage64 sR0 = mk_stage64(Rsel + (long)t0*128, 128, At, tid);
  const Stage64 sR1 = mk_stage64(Rsel + ((long)TOKENS + t0)*128, 128, Gt, tid);
  for(int k0=0; k0<128; k0+=64){
    do_stage64(sB, k0); do_stage64(sR0, k0); do_stage64(sR1, k0);
    __syncthreads();
    #pragma unroll
    for(int s=0;s<2;s++){
      f16x8 a0[4], a1[4];
      #pragma unroll
      for(int i=0;i<4;i++){ a0[i] = fragh64(At, wm + i*16 + fr, s, quad);
                            a1[i] = fragh64(Gt, wm + i*16 + fr, s, quad); }
      #pragma unroll
      for(int j=0;j<4;j++){
        const f16x8 bf = fragh64(Bt, wn + j*16 + fr, s, quad);
        #pragma unroll
        for(int i=0;i<4;i++){
          l0[i][j] = __builtin_amdgcn_mfma_f32_16x16x32_f16(a0[i], bf, l0[i][j], 0,0,0);
          l1[i][j] = __builtin_amdgcn_mfma_f32_16x16x32_f16(a1[i], bf, l1[i][j], 0,0,0);
        }
      }
    }
    __syncthreads();
  }
  // chunk-major output: base for this mat's 16 chunks
  short* o = LF + (long)(blockIdx.y*44 + blockIdx.x)*65536 + ((long)blockIdx.z*16*256 + tid)*8;
  #pragma unroll
  for(int i=0;i<4;i++){
    s16x8 p0a, p0b, p1a, p1b;
    #pragma unroll
    for(int r=0;r<4;r++){
      p0a[r]   = f2h(l0[i][0][r]); p0a[4+r] = f2h(l0[i][1][r]);
      p0b[r]   = f2h(l0[i][2][r]); p0b[4+r] = f2h(l0[i][3][r]);
      p1a[r]   = f2h(l1[i][0][r]); p1a[4+r] = f2h(l1[i][1][r]);
      p1b[r]   = f2h(l1[i][2][r]); p1b[4+r] = f2h(l1[i][3][r]);
    }
    *(s16x8*)(o + (i*2+0)*2048)     = p0a;   // q = z*16 + 0*8 + i*2 + 0
    *(s16x8*)(o + (i*2+1)*2048)     = p0b;   // q = z*16 + 0*8 + i*2 + 1
    *(s16x8*)(o + (8 + i*2+0)*2048) = p1a;   // q = z*16 + 1*8 + i*2 + 0
    *(s16x8*)(o + (8 + i*2+1)*2048) = p1b;   // q = z*16 + 1*8 + i*2 + 1
  }
}

// ---------------- K4: base up/gate GEMM (BK=32, depth-2 counted-vmcnt pipeline) ----------------
// Steady state: 18 global_load_lds in flight (3 tiles x 6); vmcnt(12) waits only the
// oldest tile => each tile's loads get ~2 full compute phases to land (T3+T4).
__global__ __launch_bounds__(256,2) void k_main(
    const short* __restrict__ xb, const short* __restrict__ wub, const short* __restrict__ wgb,
    const short* __restrict__ LF,
    const float* __restrict__ cw, unsigned short* __restrict__ ch, unsigned short* __restrict__ chsum){
  __shared__ __align__(16) short At[3][4096];
  __shared__ __align__(16) short Ut[3][4096];
  __shared__ __align__(16) short Gt[3][4096];
  const int h0 = blockIdx.x*128, t0 = blockIdx.y*128;
  const int tid = threadIdx.x, lane = tid&63, wave = tid>>6;
  const int wm=(wave>>1)*64, wn=(wave&1)*64, fr=lane&15, quad=lane>>4;
  f32x4 au[4][4], ag[4][4];
  #pragma unroll
  for(int i=0;i<4;i++)
    #pragma unroll
    for(int j=0;j<4;j++){ au[i][j]=(f32x4){0.f,0.f,0.f,0.f}; ag[i][j]=au[i][j]; }
  const Src2 sA = mk_src(xb + (long)t0*DMODEL, DMODEL, tid);
  const Src2 sU = mk_src(wub + (long)h0*DMODEL, DMODEL, tid);
  const Src2 sG = mk_src(wgb + (long)h0*DMODEL, DMODEL, tid);

  auto kstep = [&](const short* A, const short* U, const short* G){
    s16x8 af[4];
    #pragma unroll
    for(int i=0;i<4;i++) af[i] = fragb(A, wm + i*16 + fr, quad);
    #pragma unroll
    for(int j=0;j<4;j++){
      const s16x8 bu = fragb(U, wn + j*16 + fr, quad);
      const s16x8 bg = fragb(G, wn + j*16 + fr, quad);
      #pragma unroll
      for(int i=0;i<4;i++){
        au[i][j] = __builtin_amdgcn_mfma_f32_16x16x32_bf16(af[i], bu, au[i][j], 0,0,0);
        ag[i][j] = __builtin_amdgcn_mfma_f32_16x16x32_bf16(af[i], bg, ag[i][j], 0,0,0);
      }
    }
  };

  short *A0=At[0], *A1=At[1], *A2=At[2];
  short *U0=Ut[0], *U1=Ut[1], *U2=Ut[2];
  short *G0=Gt[0], *G1=Gt[1], *G2=Gt[2];
  // prologue: tiles 0,1 in flight (12 loads)
  stage2(sA, 0,  A0, tid); stage2(sU, 0,  U0, tid); stage2(sG, 0,  G0, tid);
  stage2(sA, 32, A1, tid); stage2(sU, 32, U1, tid); stage2(sG, 32, G1, tid);
  for(int s=0; s<62; s++){
    const int k2 = (s+2)*32;
    stage2(sA, k2, A2, tid); stage2(sU, k2, U2, tid); stage2(sG, k2, G2, tid);  // 18 in flight
    asm volatile("s_waitcnt vmcnt(12)" ::: "memory");   // oldest tile landed
    __builtin_amdgcn_s_barrier();
    __builtin_amdgcn_sched_barrier(0);
    kstep(A0, U0, G0);
    __builtin_amdgcn_sched_barrier(0);
    __builtin_amdgcn_s_barrier();                        // reads of A0 done before overwrite
    short* t;
    t=A0; A0=A1; A1=A2; A2=t;
    t=U0; U0=U1; U1=U2; U2=t;
    t=G0; G0=G1; G1=G2; G2=t;
  }
  // tail step 62: 12 outstanding -> wait 6
  asm volatile("s_waitcnt vmcnt(6)" ::: "memory");
  __builtin_amdgcn_s_barrier();
  __builtin_amdgcn_sched_barrier(0);
  kstep(A0, U0, G0);
  __builtin_amdgcn_sched_barrier(0);
  __builtin_amdgcn_s_barrier();
  // tail step 63: drain
  asm volatile("s_waitcnt vmcnt(0)" ::: "memory");
  __builtin_amdgcn_s_barrier();
  __builtin_amdgcn_sched_barrier(0);
  kstep(A1, U1, G1);

  // ---- epilogue: chunk-major LoRA loads (coalesced 16B), silu*gate, scale, 3 streams ----
  const short* Lf = LF + (long)(blockIdx.y*44 + blockIdx.x)*65536 + (long)tid*8;
  #pragma unroll
  for(int i=0;i<4;i++){
    f16x8 Uv0[2], Uv1[2], Gv0[2], Gv1[2];
    Uv0[0] = *(const f16x8*)(Lf + (i*2+0)*2048);       Uv0[1] = *(const f16x8*)(Lf + (i*2+1)*2048);
    Uv1[0] = *(const f16x8*)(Lf + (8+i*2+0)*2048);     Uv1[1] = *(const f16x8*)(Lf + (8+i*2+1)*2048);
    Gv0[0] = *(const f16x8*)(Lf + (16+i*2+0)*2048);    Gv0[1] = *(const f16x8*)(Lf + (16+i*2+1)*2048);
    Gv1[0] = *(const f16x8*)(Lf + (24+i*2+0)*2048);    Gv1[1] = *(const f16x8*)(Lf + (24+i*2+1)*2048);
    #pragma unroll
    for(int reg=0;reg<4;reg++){
      const int tl = wm + i*16 + quad*4 + reg;
      const float2 cc = *(const float2*)(cw + (long)(t0+tl)*2);   // wave-broadcast, L1-hit
      const float c0 = cc.x, c1 = cc.y;
      const long row0 = (long)(t0+tl)*DHID + h0;
      const long row1 = ((long)TOKENS + t0+tl)*DHID + h0;
      unsigned short* r0 = ch + row0;
      unsigned short* r1 = ch + row1;
      unsigned short* rs = chsum + row0;
      #pragma unroll
      for(int j=0;j<4;j++){
        const int hl = wn + j*16 + fr;
        const int q = (j&1)*4 + reg, hv = j>>1;
        const float u0 = au[i][j][reg] + (float)Uv0[hv][q];
        const float g0 = ag[i][j][reg] + (float)Gv0[hv][q];
        const float h0v = (u0 / (1.f + __expf(-u0))) * g0;
        const float u1 = au[i][j][reg] + (float)Uv1[hv][q];
        const float g1 = ag[i][j][reg] + (float)Gv1[hv][q];
        const float h1v = (u1 / (1.f + __expf(-u1))) * g1;
        const float v0 = c0*h0v, v1 = c1*h1v;
        r0[hl] = (unsigned short)f2bf(v0);
        r1[hl] = (unsigned short)f2bf(v1);
        rs[hl] = (unsigned short)f2bf(v0+v1);
      }
    }
  }
}

// ---------------- K5: RD[t][k][c] = ch_k @ daA^T (ksplit=16, atomics, depth-2 pipeline) ----------------
__global__ __launch_bounds__(256,2) void k_rd(
    const unsigned short* __restrict__ ch, const short* __restrict__ daA,
    float* __restrict__ RD){
  __shared__ __align__(16) short At[3][4096];
  __shared__ __align__(16) short Bt[3][4096];
  const int slot = blockIdx.x>>4, ks = blockIdx.x&15;
  const int t0 = blockIdx.y*128;
  const int tid = threadIdx.x, lane = tid&63, wave = tid>>6;
  const int wm=(wave>>1)*64, wn=(wave&1)*64, fr=lane&15, quad=lane>>4;
  f32x4 acc[4][4];
  #pragma unroll
  for(int i=0;i<4;i++)
    #pragma unroll
    for(int j=0;j<4;j++) acc[i][j]=(f32x4){0.f,0.f,0.f,0.f};
  const Src2 sA = mk_src((const short*)ch + ((long)slot*TOKENS + t0)*DHID, DHID, tid);
  const Src2 sB = mk_src(daA, DHID, tid);
  const int kbeg = ks*352;

  auto kstep = [&](const short* A, const short* B){
    s16x8 af[4];
    #pragma unroll
    for(int i=0;i<4;i++) af[i] = fragb(A, wm + i*16 + fr, quad);
    #pragma unroll
    for(int j=0;j<4;j++){
      const s16x8 bf = fragb(B, wn + j*16 + fr, quad);
      #pragma unroll
      for(int i=0;i<4;i++)
        acc[i][j] = __builtin_amdgcn_mfma_f32_16x16x32_bf16(af[i], bf, acc[i][j], 0,0,0);
    }
  };

  short *A0=At[0], *A1=At[1], *A2=At[2];
  short *B0=Bt[0], *B1=Bt[1], *B2=Bt[2];
  stage2(sA, kbeg,    A0, tid); stage2(sB, kbeg,    B0, tid);
  stage2(sA, kbeg+32, A1, tid); stage2(sB, kbeg+32, B1, tid);
  for(int s=0; s<9; s++){
    const int k2 = kbeg + (s+2)*32;
    stage2(sA, k2, A2, tid); stage2(sB, k2, B2, tid);   // 12 in flight
    asm volatile("s_waitcnt vmcnt(8)" ::: "memory");
    __builtin_amdgcn_s_barrier();
    __builtin_amdgcn_sched_barrier(0);
    kstep(A0, B0);
    __builtin_amdgcn_sched_barrier(0);
    __builtin_amdgcn_s_barrier();
    short* t;
    t=A0; A0=A1; A1=A2; A2=t;
    t=B0; B0=B1; B1=B2; B2=t;
  }
  asm volatile("s_waitcnt vmcnt(4)" ::: "memory");
  __builtin_amdgcn_s_barrier();
  __builtin_amdgcn_sched_barrier(0);
  kstep(A0, B0);
  __builtin_amdgcn_sched_barrier(0);
  __builtin_amdgcn_s_barrier();
  asm volatile("s_waitcnt vmcnt(0)" ::: "memory");
  __builtin_amdgcn_s_barrier();
  __builtin_amdgcn_sched_barrier(0);
  kstep(A1, B1);

  #pragma unroll
  for(int i=0;i<4;i++)
    #pragma unroll
    for(int j=0;j<4;j++){
      const int rbase = wm + i*16 + quad*4, col = wn + j*16 + fr;
      #pragma unroll
      for(int reg=0;reg<4;reg++)
        atomicAdd(&RD[((long)(t0+rbase+reg)*2 + slot)*128 + col], acc[i][j][reg]);
    }
}

// ---------------- K5b: RDhat[t][c] (f16) = alpha * RD at selected expert blocks ----------------
__global__ void k_scatter(const float* __restrict__ RD, const int* __restrict__ sel,
                          __half* __restrict__ RDhat){
  const int idx = blockIdx.x*256 + threadIdx.x;   // over T*128
  const int t = idx>>7, c = idx&127, e = c>>4;
  const int s0 = sel[t*2], s1 = sel[t*2+1];
  float v = 0.f;
  if(e == s0) v = LALPHA * RD[((long)t*2+0)*128 + c];
  else if(e == s1) v = LALPHA * RD[((long)t*2+1)*128 + c];
  RDhat[idx] = __float2half(v);
}

// ---------------- K6: out += chsum @ wdb^T (split-K=2, depth-2 pipeline) + RDhat @ wdbcat^T ----------------
__global__ __launch_bounds__(256,2) void k_down(
    const unsigned short* __restrict__ chsum, const short* __restrict__ wdb,
    const short* __restrict__ RDhat, const short* __restrict__ wdbcat,
    float* __restrict__ out){
  __shared__ __align__(16) short At[3][4096];
  __shared__ __align__(16) short Bt[3][4096];
  const int d0 = blockIdx.x*128, t0 = blockIdx.y*128, ks = blockIdx.z;
  const int tid = threadIdx.x, lane = tid&63, wave = tid>>6;
  const int wm=(wave>>1)*64, wn=(wave&1)*64, fr=lane&15, quad=lane>>4;
  f32x4 acc[4][4];
  #pragma unroll
  for(int i=0;i<4;i++)
    #pragma unroll
    for(int j=0;j<4;j++) acc[i][j]=(f32x4){0.f,0.f,0.f,0.f};
  const Src2 sA = mk_src((const short*)chsum + (long)t0*DHID, DHID, tid);
  const Src2 sB = mk_src(wdb + (long)d0*DHID, DHID, tid);
  const int kbeg = ks*2816;

  auto kstep = [&](const short* A, const short* B){
    s16x8 af[4];
    #pragma unroll
    for(int i=0;i<4;i++) af[i] = fragb(A, wm + i*16 + fr, quad);
    #pragma unroll
    for(int j=0;j<4;j++){
      const s16x8 bf = fragb(B, wn + j*16 + fr, quad);
      #pragma unroll
      for(int i=0;i<4;i++)
        acc[i][j] = __builtin_amdgcn_mfma_f32_16x16x32_bf16(af[i], bf, acc[i][j], 0,0,0);
    }
  };

  short *A0=At[0], *A1=At[1], *A2=At[2];
  short *B0=Bt[0], *B1=Bt[1], *B2=Bt[2];
  stage2(sA, kbeg,    A0, tid); stage2(sB, kbeg,    B0, tid);
  stage2(sA, kbeg+32, A1, tid); stage2(sB, kbeg+32, B1, tid);
  for(int s=0; s<86; s++){
    const int k2 = kbeg + (s+2)*32;
    stage2(sA, k2, A2, tid); stage2(sB, k2, B2, tid);   // 12 in flight
    asm volatile("s_waitcnt vmcnt(8)" ::: "memory");
    __builtin_amdgcn_s_barrier();
    __builtin_amdgcn_sched_barrier(0);
    kstep(A0, B0);
    __builtin_amdgcn_sched_barrier(0);
    __builtin_amdgcn_s_barrier();
    short* t;
    t=A0; A0=A1; A1=A2; A2=t;
    t=B0; B0=B1; B1=B2; B2=t;
  }
  asm volatile("s_waitcnt vmcnt(4)" ::: "memory");
  __builtin_amdgcn_s_barrier();
  __builtin_amdgcn_sched_barrier(0);
  kstep(A0, B0);
  __builtin_amdgcn_sched_barrier(0);
  __builtin_amdgcn_s_barrier();
  asm volatile("s_waitcnt vmcnt(0)" ::: "memory");
  __builtin_amdgcn_s_barrier();
  __builtin_amdgcn_sched_barrier(0);
  kstep(A1, B1);
  __builtin_amdgcn_s_barrier();    // all reads done before f16 tail re-stages

  if(ks == 0){
    // LoRA-down phase: K=128 over RDhat (f16) @ wdbcat (f16), simple dbuf (syncthreads)
    const Src2 sAh = mk_src(RDhat + (long)t0*128, 128, tid);
    const Src2 sBh = mk_src(wdbcat + (long)d0*128, 128, tid);
    stage2(sAh, 0, At[0], tid); stage2(sBh, 0, Bt[0], tid);
    __syncthreads();
    int cur = 0;
    for(int k0=0; k0<128; k0+=32){
      const int nxt = cur^1;
      if(k0+32 < 128){
        stage2(sAh, k0+32, At[nxt], tid);
        stage2(sBh, k0+32, Bt[nxt], tid);
      }
      __builtin_amdgcn_sched_barrier(0);
      f16x8 af[4];
      #pragma unroll
      for(int i=0;i<4;i++) af[i] = fragh(At[cur], wm + i*16 + fr, quad);
      #pragma unroll
      for(int j=0;j<4;j++){
        const f16x8 bf = fragh(Bt[cur], wn + j*16 + fr, quad);
        #pragma unroll
        for(int i=0;i<4;i++)
          acc[i][j] = __builtin_amdgcn_mfma_f32_16x16x32_f16(af[i], bf, acc[i][j], 0,0,0);
      }
      __syncthreads();
      cur = nxt;
    }
  }
  #pragma unroll
  for(int i=0;i<4;i++)
    #pragma unroll
    for(int j=0;j<4;j++){
      const int rbase = wm + i*16 + quad*4, col = wn + j*16 + fr;
      #pragma unroll
      for(int reg=0;reg<4;reg++)
        atomicAdd(&out[(long)(t0+rbase+reg)*DMODEL + d0 + col], acc[i][j][reg]);
    }
}

extern "C" void kernel_launch(void* const* d_in, const int* in_sizes, int n_in,
                              void* d_out, int out_size, void* d_ws, size_t ws_size,
                              hipStream_t stream){
  (void)in_sizes; (void)n_in; (void)out_size; (void)ws_size;
  const float* x      = (const float*)d_in[0];
  const float* gate_w = (const float*)d_in[1];
  const float* w_up   = (const float*)d_in[2];
  const float* w_gate = (const float*)d_in[3];
  const float* w_down = (const float*)d_in[4];
  const float* up_A   = (const float*)d_in[5];
  const float* up_B   = (const float*)d_in[6];
  const float* gate_A = (const float*)d_in[7];
  const float* gate_B = (const float*)d_in[8];
  const float* down_A = (const float*)d_in[9];
  const float* down_B = (const float*)d_in[10];
  float* out = (float*)d_out;

  char* ws = (char*)d_ws;
  size_t off = 0;
  auto alloc = [&](size_t bytes){ void* p = ws + off; off += (bytes + 255) & ~(size_t)255; return p; };
  short* xb       = (short*)alloc((size_t)TOKENS*DMODEL*2);
  short* wub      = (short*)alloc((size_t)DHID*DMODEL*2);
  short* wgb      = (short*)alloc((size_t)DHID*DMODEL*2);
  short* wdb      = (short*)alloc((size_t)DMODEL*DHID*2);
  short* daA      = (short*)alloc((size_t)128*DHID*2);
  short* acat     = (short*)alloc((size_t)256*DMODEL*2);
  short* upBcat   = (short*)alloc((size_t)DHID*128*2);
  short* gateBcat = (short*)alloc((size_t)DHID*128*2);
  short* wdbcat   = (short*)alloc((size_t)DMODEL*128*2);
  unsigned short* ch    = (unsigned short*)alloc((size_t)2*TOKENS*DHID*2);
  unsigned short* chsum = (unsigned short*)alloc((size_t)TOKENS*DHID*2);
  short* LF     = (short*)alloc((size_t)704*65536*2);   // chunk-major fragment LoRA deltas
  float* Rall   = (float*)alloc((size_t)TOKENS*256*4);
  short* RselU  = (short*)alloc((size_t)2*TOKENS*128*2);
  short* RselG  = (short*)alloc((size_t)2*TOKENS*128*2);
  float* RD     = (float*)alloc((size_t)TOKENS*2*128*4);
  __half* RDhat = (__half*)alloc((size_t)TOKENS*128*2);
  int*   sel    = (int*)alloc((size_t)TOKENS*2*4);
  float* topv   = (float*)alloc((size_t)TOKENS*2*4);
  float* cw     = (float*)alloc((size_t)TOKENS*2*4);

  (void)hipMemsetAsync(RD, 0, (size_t)TOKENS*2*128*4, stream);
  (void)hipMemsetAsync(Rall, 0, (size_t)TOKENS*256*4, stream);
  (void)hipMemsetAsync(out, 0, (size_t)TOKENS*DMODEL*4, stream);
  k_cast<<<40768, 256, 0, stream>>>(x, w_up, w_gate, w_down, up_A, gate_A, down_A,
                                    up_B, gate_B, down_B,
                                    xb, wub, wgb, wdb, daA, acat, upBcat, gateBcat, wdbcat);
  k_router<<<512, 256, 0, stream>>>(x, gate_w, sel, topv);
  k_softmax<<<4, 256, 0, stream>>>(topv, cw);
  k_rank<<<dim3(2,16,8), 256, 0, stream>>>(xb, acat, Rall);
  k_rsel<<<2048, 256, 0, stream>>>(Rall, sel, RselU, RselG);
  k_lora<<<dim3(44,16,2), 256, 0, stream>>>(RselU, RselG, upBcat, gateBcat, LF);
  k_main<<<dim3(44,16), 256, 0, stream>>>(xb, wub, wgb, LF, cw, ch, chsum);
  k_rd<<<dim3(32,16), 256, 0, stream>>>(ch, daA, RD);
  k_scatter<<<1024, 256, 0, stream>>>(RD, sel, RDhat);
  k_down<<<dim3(16,16,2), 256, 0, stream>>>(chsum, wdb, (const short*)RDhat, wdbcat, out);
}

// Round 5
// 533.775 us; speedup vs baseline: 1.0961x; 1.0078x over previous
//
#include <hip/hip_runtime.h>
#include <hip/hip_fp16.h>
#include <cmath>

#define TOKENS 2048
#define DMODEL 2048
#define DHID   5632
#define NEXP   8
#define RANK   16
#define LALPHA 2.0f

typedef __attribute__((ext_vector_type(4))) float f32x4;
typedef __attribute__((ext_vector_type(8))) short s16x8;
typedef __attribute__((ext_vector_type(4))) short s16x4;
typedef __attribute__((ext_vector_type(8))) _Float16 f16x8;

__device__ __forceinline__ short f2bf(float f){
  unsigned u = __float_as_uint(f);
  u += 0x7fffu + ((u >> 16) & 1u);
  return (short)(u >> 16);
}
__device__ __forceinline__ short f2h(float f){
  return (short)__half_as_ushort(__float2half(f));
}

// ---------- BK=32 staging of a 128x32 tile (8KB), dest selectable ----------
struct Src2 { const short* s0; const short* s1; };

__device__ __forceinline__ Src2 mk_src(const short* g, long ld, int tid){
  Src2 st;
  const int L0 = tid,      r0 = L0>>2, c0 = ((L0&3) - (r0>>1)) & 3;
  const int L1 = 256+tid,  r1 = L1>>2, c1 = ((L1&3) - (r1>>1)) & 3;
  st.s0 = g + (long)r0*ld + c0*8;
  st.s1 = g + (long)r1*ld + c1*8;
  return st;
}
__device__ __forceinline__ void stage2(const Src2& st, int k0, short* t, int tid){
  __builtin_amdgcn_global_load_lds((const __attribute__((address_space(1))) void*)(st.s0 + k0),
                                   (__attribute__((address_space(3))) void*)(t + tid*8), 16, 0, 0);
  __builtin_amdgcn_global_load_lds((const __attribute__((address_space(1))) void*)(st.s1 + k0),
                                   (__attribute__((address_space(3))) void*)(t + (256+tid)*8), 16, 0, 0);
}
__device__ __forceinline__ s16x8 fragb(const short* t, int row, int quad){
  const int p = (quad + (row>>1)) & 3;
  return *(const s16x8*)(t + (row*4 + p)*8);
}
__device__ __forceinline__ f16x8 fragh(const short* t, int row, int quad){
  const int p = (quad + (row>>1)) & 3;
  return *(const f16x8*)(t + (row*4 + p)*8);
}

// ---------- BK=64 tiles: 8-chunk row-rotation swizzle ----------
struct Stage64 { const short* g; short* t; int off[4]; int dof; };

__device__ __forceinline__ Stage64 mk_stage64(const short* g, long ld, short* t, int tid){
  Stage64 st; st.g = g; st.t = t;
  #pragma unroll
  for(int p=0;p<4;p++){
    const int L = p*256 + tid;
    const int r = L>>3, cp = L&7;
    const int c = (cp - (r&7)) & 7;
    st.off[p] = r*(int)ld + c*8;
  }
  st.dof = tid*8;
  return st;
}
__device__ __forceinline__ void do_stage64(const Stage64& st, int k0){
  #pragma unroll
  for(int p=0;p<4;p++)
    __builtin_amdgcn_global_load_lds(
      (const __attribute__((address_space(1))) void*)(st.g + st.off[p] + k0),
      (__attribute__((address_space(3))) void*)(st.t + st.dof + p*2048), 16, 0, 0);
}
__device__ __forceinline__ s16x8 fragb64(const short* t, int row, int ksub, int quad){
  const int c = ksub*4 + quad;
  const int p = (c + (row&7)) & 7;
  return *(const s16x8*)(t + (row*8 + p)*8);
}
__device__ __forceinline__ f16x8 fragh64(const short* t, int row, int ksub, int quad){
  const int c = ksub*4 + quad;
  const int p = (c + (row&7)) & 7;
  return *(const f16x8*)(t + (row*8 + p)*8);
}

#define GLL(SRC, DST) __builtin_amdgcn_global_load_lds( \
    (const __attribute__((address_space(1))) void*)(SRC), \
    (__attribute__((address_space(3))) void*)(DST), 16, 0, 0)

// ---------------- K0: cast/gather all GEMM operands ----------------
__global__ void k_cast(const float* __restrict__ x, const float* __restrict__ w_up,
                       const float* __restrict__ w_gate, const float* __restrict__ w_down,
                       const float* __restrict__ upA, const float* __restrict__ gateA,
                       const float* __restrict__ downA, const float* __restrict__ upB,
                       const float* __restrict__ gateB, const float* __restrict__ downB,
                       short* __restrict__ xb, short* __restrict__ wub, short* __restrict__ wgb,
                       short* __restrict__ wdb, short* __restrict__ daA, short* __restrict__ acat,
                       short* __restrict__ upBcat, short* __restrict__ gateBcat, short* __restrict__ wdbcat){
  const long e0 = 4194304, e1 = 15728640, e2 = 27262976, e3 = 38797312;
  const long e4 = 39518208, e5 = 40042496, e6 = 40763392, e7 = 41484288, e8 = 41746432;
  const long i = ((long)blockIdx.x*256 + threadIdx.x) * 4;
  if(i >= e8) return;
  const float* src; short* dst; long l; int fp16 = 0;
  if(i < e0){ src = x; dst = xb; l = i; }
  else if(i < e1){ src = w_up; dst = wub; l = i - e0; }
  else if(i < e2){ src = w_gate; dst = wgb; l = i - e1; }
  else if(i < e3){ src = w_down; dst = wdb; l = i - e2; }
  else if(i < e4){ src = downA; dst = daA; l = i - e3; }   // daA[c][h] == downA flat
  else if(i < e5){ // acat[c][d] = (pj?gateA:upA)[e][r][d], c = e*32+pj*16+r
    l = i - e4;
    const long c = l>>11;
    const long e = c>>5, pj = (c>>4)&1, r = c&15;
    src = (pj ? gateA : upA) + ((e*RANK + r)<<11) + (l&2047) - l;
    dst = acat;
  }
  else if(i < e6){ // upBcat[h][e*16+r] = upB[e][h][r]  (f16)
    l = i - e5;
    const long h = l>>7, c = l&127, e = c>>4, r = c&15;
    src = upB + ((e*DHID + h)*RANK + r) - l;
    dst = upBcat; fp16 = 1;
  }
  else if(i < e7){ // gateBcat
    l = i - e6;
    const long h = l>>7, c = l&127, e = c>>4, r = c&15;
    src = gateB + ((e*DHID + h)*RANK + r) - l;
    dst = gateBcat; fp16 = 1;
  }
  else { // wdbcat[d][e*16+r] = downB[e][d][r]  (f16)
    l = i - e7;
    const long d = l>>7, c = l&127, e = c>>4, r = c&15;
    src = downB + ((e*DMODEL + d)*RANK + r) - l;
    dst = wdbcat; fp16 = 1;
  }
  const float4 v = *(const float4*)(src + l);
  s16x4 o;
  if(fp16){ o[0]=f2h(v.x); o[1]=f2h(v.y); o[2]=f2h(v.z); o[3]=f2h(v.w); }
  else    { o[0]=f2bf(v.x); o[1]=f2bf(v.y); o[2]=f2bf(v.z); o[3]=f2bf(v.w); }
  *(s16x4*)(dst + l) = o;
}

// ---------------- K1: router logits (fp32, one wave per token) + top-2 ----------------
__global__ void k_router(const float* __restrict__ x, const float* __restrict__ gw,
                         int* __restrict__ sel, float* __restrict__ topv){
  const int t = blockIdx.x*4 + (threadIdx.x>>6);
  const int lane = threadIdx.x & 63;
  const float* xr = x + (long)t * DMODEL;
  float acc[NEXP];
  #pragma unroll
  for(int e=0;e<NEXP;e++) acc[e]=0.f;
  #pragma unroll
  for(int it=0; it<8; it++){
    const int d = it*256 + lane*4;
    const float4 xv = *(const float4*)(xr + d);
    #pragma unroll
    for(int e=0;e<NEXP;e++){
      const float4 wv = *(const float4*)(gw + e*DMODEL + d);
      acc[e] += xv.x*wv.x + xv.y*wv.y + xv.z*wv.z + xv.w*wv.w;
    }
  }
  #pragma unroll
  for(int e=0;e<NEXP;e++){
    #pragma unroll
    for(int off=32; off; off>>=1) acc[e] += __shfl_down(acc[e], off, 64);
  }
  if(lane==0){
    int i0=0;
    #pragma unroll
    for(int e=1;e<NEXP;e++) if(acc[e]>acc[i0]) i0=e;
    int i1=-1;
    #pragma unroll
    for(int e=0;e<NEXP;e++){ if(e==i0) continue; if(i1<0 || acc[e]>acc[i1]) i1=e; }
    sel[t*2+0]=i0; sel[t*2+1]=i1;
    topv[t*2+0]=acc[i0]; topv[t*2+1]=acc[i1];
  }
}

// ---------------- K2: softmax over the SEQUENCE axis (faithful) ----------------
__global__ void k_softmax(const float* __restrict__ topv, float* __restrict__ cw){
  const int b = blockIdx.x >> 1, k = blockIdx.x & 1;
  const int base = b*1024;
  __shared__ float red[256];
  float v[4];
  float mx = -1e30f;
  #pragma unroll
  for(int i=0;i<4;i++){
    int s = threadIdx.x + i*256;
    v[i] = topv[(base+s)*2 + k];
    mx = fmaxf(mx, v[i]);
  }
  red[threadIdx.x]=mx; __syncthreads();
  for(int o=128;o;o>>=1){ if(threadIdx.x<o) red[threadIdx.x]=fmaxf(red[threadIdx.x],red[threadIdx.x+o]); __syncthreads(); }
  mx = red[0]; __syncthreads();
  float sum=0.f;
  #pragma unroll
  for(int i=0;i<4;i++){ v[i]=__expf(v[i]-mx); sum+=v[i]; }
  red[threadIdx.x]=sum; __syncthreads();
  for(int o=128;o;o>>=1){ if(threadIdx.x<o) red[threadIdx.x]+=red[threadIdx.x+o]; __syncthreads(); }
  const float inv = 1.f/red[0];
  #pragma unroll
  for(int i=0;i<4;i++){
    int s = threadIdx.x + i*256;
    cw[(base+s)*2+k] = v[i]*inv;
  }
}

// ---------------- K3: Rall += X @ Acat^T (split-K=8, BK=64, atomics) ----------------
__global__ __launch_bounds__(256,2) void k_rank(
    const short* __restrict__ xb, const short* __restrict__ acat, float* __restrict__ Rall){
  __shared__ __align__(16) short At[8192];
  __shared__ __align__(16) short Bt[8192];
  const int c0 = blockIdx.x*128, t0 = blockIdx.y*128;
  const int kbeg = blockIdx.z*256;
  const int tid = threadIdx.x, lane = tid&63, wave = tid>>6;
  const int wm=(wave>>1)*64, wn=(wave&1)*64, fr=lane&15, quad=lane>>4;
  f32x4 acc[4][4];
  #pragma unroll
  for(int i=0;i<4;i++)
    #pragma unroll
    for(int j=0;j<4;j++) acc[i][j]=(f32x4){0.f,0.f,0.f,0.f};
  const Stage64 sA = mk_stage64(xb + (long)t0*DMODEL, DMODEL, At, tid);
  const Stage64 sB = mk_stage64(acat + (long)c0*DMODEL, DMODEL, Bt, tid);
  for(int k0=kbeg; k0<kbeg+256; k0+=64){
    do_stage64(sA, k0); do_stage64(sB, k0);
    __syncthreads();
    #pragma unroll
    for(int s=0;s<2;s++){
      s16x8 af[4];
      #pragma unroll
      for(int i=0;i<4;i++) af[i] = fragb64(At, wm + i*16 + fr, s, quad);
      #pragma unroll
      for(int j=0;j<4;j++){
        const s16x8 bf = fragb64(Bt, wn + j*16 + fr, s, quad);
        #pragma unroll
        for(int i=0;i<4;i++)
          acc[i][j] = __builtin_amdgcn_mfma_f32_16x16x32_bf16(af[i], bf, acc[i][j], 0,0,0);
      }
    }
    __syncthreads();
  }
  #pragma unroll
  for(int i=0;i<4;i++)
    #pragma unroll
    for(int j=0;j<4;j++){
      const int rbase = wm + i*16 + quad*4, col = wn + j*16 + fr;
      #pragma unroll
      for(int reg=0;reg<4;reg++)
        atomicAdd(&Rall[(long)(t0+rbase+reg)*256 + c0 + col], acc[i][j][reg]);
    }
}

// ---------------- K3b: Rsel[k][t][e*16+r] = (e==sel_k) ? alpha*Rall : 0  (f16) ----------------
__global__ void k_rsel(const float* __restrict__ Rall, const int* __restrict__ sel,
                       short* __restrict__ RselU, short* __restrict__ RselG){
  const int idx = blockIdx.x*256 + threadIdx.x;      // [2][TOKENS][128]
  const int c = idx & 127, t = (idx>>7) & (TOKENS-1), k = idx>>18;
  const int e = c>>4, r = c&15;
  const int s = sel[t*2+k];
  const int m = (e==s);
  RselU[idx] = f2h(m ? LALPHA*Rall[(long)t*256 + e*32 + r]      : 0.f);
  RselG[idx] = f2h(m ? LALPHA*Rall[(long)t*256 + e*32 + 16 + r] : 0.f);
}

// ---------------- K3c: LoRA up/gate deltas, FRAGMENT ORDER, chunk-major (coalesced) ----------------
// LF layout: per block blin = by*44+bx: 32 chunks q of [256 threads][8 halves].
//   q = mat(z)*16 + slot*8 + i*2 + h ;  addr = blin*65536 + (q*256 + tid)*8
__global__ __launch_bounds__(256,2) void k_lora(
    const short* __restrict__ RselU, const short* __restrict__ RselG,
    const short* __restrict__ upBcat, const short* __restrict__ gateBcat,
    short* __restrict__ LF){
  __shared__ __align__(16) short At[8192];   // Rsel slot0 tile
  __shared__ __align__(16) short Gt[8192];   // Rsel slot1 tile
  __shared__ __align__(16) short Bt[8192];   // Bcat tile
  const int h0 = blockIdx.x*128, t0 = blockIdx.y*128;
  const short* Rsel = blockIdx.z ? RselG : RselU;
  const short* Bcat = blockIdx.z ? gateBcat : upBcat;
  const int tid = threadIdx.x, lane = tid&63, wave = tid>>6;
  const int wm=(wave>>1)*64, wn=(wave&1)*64, fr=lane&15, quad=lane>>4;
  f32x4 l0[4][4], l1[4][4];
  #pragma unroll
  for(int i=0;i<4;i++)
    #pragma unroll
    for(int j=0;j<4;j++){ l0[i][j]=(f32x4){0.f,0.f,0.f,0.f}; l1[i][j]=l0[i][j]; }
  const Stage64 sB  = mk_stage64(Bcat + (long)h0*128, 128, Bt, tid);
  const Stage64 sR0 = mk_stage64(Rsel + (long)t0*128, 128, At, tid);
  const Stage64 sR1 = mk_stage64(Rsel + ((long)TOKENS + t0)*128, 128, Gt, tid);
  for(int k0=0; k0<128; k0+=64){
    do_stage64(sB, k0); do_stage64(sR0, k0); do_stage64(sR1, k0);
    __syncthreads();
    #pragma unroll
    for(int s=0;s<2;s++){
      f16x8 a0[4], a1[4];
      #pragma unroll
      for(int i=0;i<4;i++){ a0[i] = fragh64(At, wm + i*16 + fr, s, quad);
                            a1[i] = fragh64(Gt, wm + i*16 + fr, s, quad); }
      #pragma unroll
      for(int j=0;j<4;j++){
        const f16x8 bf = fragh64(Bt, wn + j*16 + fr, s, quad);
        #pragma unroll
        for(int i=0;i<4;i++){
          l0[i][j] = __builtin_amdgcn_mfma_f32_16x16x32_f16(a0[i], bf, l0[i][j], 0,0,0);
          l1[i][j] = __builtin_amdgcn_mfma_f32_16x16x32_f16(a1[i], bf, l1[i][j], 0,0,0);
        }
      }
    }
    __syncthreads();
  }
  short* o = LF + (long)(blockIdx.y*44 + blockIdx.x)*65536 + ((long)blockIdx.z*16*256 + tid)*8;
  #pragma unroll
  for(int i=0;i<4;i++){
    s16x8 p0a, p0b, p1a, p1b;
    #pragma unroll
    for(int r=0;r<4;r++){
      p0a[r]   = f2h(l0[i][0][r]); p0a[4+r] = f2h(l0[i][1][r]);
      p0b[r]   = f2h(l0[i][2][r]); p0b[4+r] = f2h(l0[i][3][r]);
      p1a[r]   = f2h(l1[i][0][r]); p1a[4+r] = f2h(l1[i][1][r]);
      p1b[r]   = f2h(l1[i][2][r]); p1b[4+r] = f2h(l1[i][3][r]);
    }
    *(s16x8*)(o + (i*2+0)*2048)     = p0a;
    *(s16x8*)(o + (i*2+1)*2048)     = p0b;
    *(s16x8*)(o + (8 + i*2+0)*2048) = p1a;
    *(s16x8*)(o + (8 + i*2+1)*2048) = p1b;
  }
}

// ---------------- K4: fused up/gate GEMM — 256x128 tile, 8 waves, 4-phase/K-tile ----------------
// 8-phase-template port (T2 swizzle + T3 fine interleave + T4 counted vmcnt + T5 setprio).
// Per K-tile (BK=64): 4 phases, each {2 global_load_lds prefetch-issue | 4 ds_read_b128 |
// 16 MFMA between raw s_barriers, setprio(1) around MFMA}. Gate once per K-tile:
// vmcnt(2) + s_barrier (2 next-next-tile loads stay in flight -> never drains mid-loop).
#define MFMA_P(P) do{ \
  __builtin_amdgcn_s_setprio(1); \
  _Pragma("unroll") for(int ks=0;ks<2;ks++){ \
    _Pragma("unroll") for(int ii=0;ii<2;ii++){ \
      _Pragma("unroll") for(int j=0;j<2;j++){ \
        aU[2*(P)+ii][j] = __builtin_amdgcn_mfma_f32_16x16x32_bf16(a[ii][ks], bu[j][ks], aU[2*(P)+ii][j],0,0,0); \
        aG[2*(P)+ii][j] = __builtin_amdgcn_mfma_f32_16x16x32_bf16(a[ii][ks], bg[j][ks], aG[2*(P)+ii][j],0,0,0); \
      }}} \
  __builtin_amdgcn_s_setprio(0); }while(0)

#define RDA(P) do{ \
  _Pragma("unroll") for(int ii=0;ii<2;ii++){ \
    _Pragma("unroll") for(int ks=0;ks<2;ks++){ \
      a[ii][ks] = fragb64(Ac, rbaseA + (2*(P)+ii)*16 + fr, ks, quad); \
    }}}while(0)

__global__ __launch_bounds__(512,2) void k_main(
    const short* __restrict__ xb, const short* __restrict__ wub, const short* __restrict__ wgb,
    const short* __restrict__ LF, const float* __restrict__ cw,
    unsigned short* __restrict__ ch, unsigned short* __restrict__ chsum){
  __shared__ __align__(16) short AL[2][16384];   // 256x64 bf16 x2
  __shared__ __align__(16) short UL[2][8192];    // 128x64 bf16 x2
  __shared__ __align__(16) short GL[2][8192];
  const int bh = blockIdx.x, bt = blockIdx.y;
  const int tid = threadIdx.x;
  const int w = tid>>6, lane = tid&63, fr = lane&15, quad = lane>>4;
  const int wq = w>>2, wh = w&3;
  const int rbaseA = wq*128;
  const int rbaseB = wh*32;
  const short* gA = xb  + (long)bt*256*DMODEL;
  const short* gU = wub + (long)bh*128*DMODEL;
  const short* gG = wgb + (long)bh*128*DMODEL;
  int offA[4], offB[2];
  #pragma unroll
  for(int k=0;k<4;k++){ const int L=k*512+tid, r=L>>3, p=L&7, c=(p-(r&7))&7; offA[k]=r*DMODEL+c*8; }
  #pragma unroll
  for(int k=0;k<2;k++){ const int L=k*512+tid, r=L>>3, p=L&7, c=(p-(r&7))&7; offB[k]=r*DMODEL+c*8; }

  f32x4 aU[8][2], aG[8][2];
  #pragma unroll
  for(int i=0;i<8;i++)
    #pragma unroll
    for(int j=0;j<2;j++){ aU[i][j]=(f32x4){0.f,0.f,0.f,0.f}; aG[i][j]=aU[i][j]; }

  short *Ac=AL[0], *An=AL[1], *Uc=UL[0], *Un=UL[1], *Gc=GL[0], *Gn=GL[1];
  // prologue: stage K-tile 0 (8 loads)
  #pragma unroll
  for(int k=0;k<4;k++) GLL(gA+offA[k], Ac+(k*512+tid)*8);
  #pragma unroll
  for(int k=0;k<2;k++){ GLL(gU+offB[k], Uc+(k*512+tid)*8); GLL(gG+offB[k], Gc+(k*512+tid)*8); }

  auto iter = [&](int k0n, bool pf) __attribute__((always_inline)) {
    // ---- phase 0: gate + B-frags + i=0,1 ----
    if(pf){ GLL(gA+offA[0]+k0n, An+(0*512+tid)*8); GLL(gA+offA[1]+k0n, An+(1*512+tid)*8);
            asm volatile("s_waitcnt vmcnt(2)" ::: "memory"); }
    else  { asm volatile("s_waitcnt vmcnt(0)" ::: "memory"); }
    __builtin_amdgcn_sched_barrier(0);
    __builtin_amdgcn_s_barrier();                 // all waves' tile-loads landed
    __builtin_amdgcn_sched_barrier(0);
    s16x8 bu[2][2], bg[2][2];
    #pragma unroll
    for(int j=0;j<2;j++)
      #pragma unroll
      for(int ks=0;ks<2;ks++){
        bu[j][ks] = fragb64(Uc, rbaseB + j*16 + fr, ks, quad);
        bg[j][ks] = fragb64(Gc, rbaseB + j*16 + fr, ks, quad);
      }
    s16x8 a[2][2];
    RDA(0);
    MFMA_P(0);
    __builtin_amdgcn_sched_barrier(0);
    __builtin_amdgcn_s_barrier();
    // ---- phase 1: i=2,3 ----
    if(pf){ GLL(gA+offA[2]+k0n, An+(2*512+tid)*8); GLL(gA+offA[3]+k0n, An+(3*512+tid)*8); }
    RDA(1);
    __builtin_amdgcn_sched_barrier(0);
    __builtin_amdgcn_s_barrier();
    __builtin_amdgcn_sched_barrier(0);
    MFMA_P(1);
    __builtin_amdgcn_sched_barrier(0);
    __builtin_amdgcn_s_barrier();
    // ---- phase 2: i=4,5 ----
    if(pf){ GLL(gU+offB[0]+k0n, Un+(0*512+tid)*8); GLL(gU+offB[1]+k0n, Un+(1*512+tid)*8); }
    RDA(2);
    __builtin_amdgcn_sched_barrier(0);
    __builtin_amdgcn_s_barrier();
    __builtin_amdgcn_sched_barrier(0);
    MFMA_P(2);
    __builtin_amdgcn_sched_barrier(0);
    __builtin_amdgcn_s_barrier();
    // ---- phase 3: i=6,7 ----
    if(pf){ GLL(gG+offB[0]+k0n, Gn+(0*512+tid)*8); GLL(gG+offB[1]+k0n, Gn+(1*512+tid)*8); }
    RDA(3);
    __builtin_amdgcn_sched_barrier(0);
    __builtin_amdgcn_s_barrier();
    __builtin_amdgcn_sched_barrier(0);
    MFMA_P(3);
    __builtin_amdgcn_sched_barrier(0);
    __builtin_amdgcn_s_barrier();
  };

  #pragma unroll 1
  for(int t=0; t<31; t++){
    iter((t+1)*64, true);
    short* tmp;
    tmp=Ac; Ac=An; An=tmp;
    tmp=Uc; Uc=Un; Un=tmp;
    tmp=Gc; Gc=Gn; Gn=tmp;
  }
  iter(0, false);

  // ---- epilogue: LF fragment-order read (remapped to old 128x128/4-wave layout) ----
  const long LFB = (long)((bt*2 + wq)*44 + bh)*65536;
  const int h0c = bh*128 + wh*32;
  #pragma unroll
  for(int i=0;i<8;i++){
    const int wp = (i>>2)*2 + (wh>>1);
    const int tidp = wp*64 + quad*16 + fr;
    const short* base = LF + LFB + (long)tidp*8;
    const int qb = (i&3)*2 + (wh&1);
    const f16x8 Uv0 = *(const f16x8*)(base + (long)(qb)*2048);
    const f16x8 Uv1 = *(const f16x8*)(base + (long)(8+qb)*2048);
    const f16x8 Gv0 = *(const f16x8*)(base + (long)(16+qb)*2048);
    const f16x8 Gv1 = *(const f16x8*)(base + (long)(24+qb)*2048);
    #pragma unroll
    for(int reg=0;reg<4;reg++){
      const int t = bt*256 + wq*128 + i*16 + quad*4 + reg;
      const float2 cc = *(const float2*)(cw + (long)t*2);
      unsigned short* r0 = ch + (long)t*DHID;
      unsigned short* r1 = ch + ((long)TOKENS + t)*DHID;
      unsigned short* rs = chsum + (long)t*DHID;
      #pragma unroll
      for(int j=0;j<2;j++){
        const int h = h0c + j*16 + fr;
        const int idx = j*4 + reg;
        const float u0 = aU[i][j][reg] + (float)Uv0[idx];
        const float g0 = aG[i][j][reg] + (float)Gv0[idx];
        const float h0v = (u0 / (1.f + __expf(-u0))) * g0;
        const float u1 = aU[i][j][reg] + (float)Uv1[idx];
        const float g1 = aG[i][j][reg] + (float)Gv1[idx];
        const float h1v = (u1 / (1.f + __expf(-u1))) * g1;
        const float v0 = cc.x*h0v, v1 = cc.y*h1v;
        r0[h] = (unsigned short)f2bf(v0);
        r1[h] = (unsigned short)f2bf(v1);
        rs[h] = (unsigned short)f2bf(v0+v1);
      }
    }
  }
}

// ---------------- K5: RD[t][k][c] = ch_k @ daA^T (ksplit=16, atomics, depth-2 pipeline) ----------------
__global__ __launch_bounds__(256,2) void k_rd(
    const unsigned short* __restrict__ ch, const short* __restrict__ daA,
    float* __restrict__ RD){
  __shared__ __align__(16) short At[3][4096];
  __shared__ __align__(16) short Bt[3][4096];
  const int slot = blockIdx.x>>4, ks = blockIdx.x&15;
  const int t0 = blockIdx.y*128;
  const int tid = threadIdx.x, lane = tid&63, wave = tid>>6;
  const int wm=(wave>>1)*64, wn=(wave&1)*64, fr=lane&15, quad=lane>>4;
  f32x4 acc[4][4];
  #pragma unroll
  for(int i=0;i<4;i++)
    #pragma unroll
    for(int j=0;j<4;j++) acc[i][j]=(f32x4){0.f,0.f,0.f,0.f};
  const Src2 sA = mk_src((const short*)ch + ((long)slot*TOKENS + t0)*DHID, DHID, tid);
  const Src2 sB = mk_src(daA, DHID, tid);
  const int kbeg = ks*352;

  auto kstep = [&](const short* A, const short* B){
    s16x8 af[4];
    #pragma unroll
    for(int i=0;i<4;i++) af[i] = fragb(A, wm + i*16 + fr, quad);
    #pragma unroll
    for(int j=0;j<4;j++){
      const s16x8 bf = fragb(B, wn + j*16 + fr, quad);
      #pragma unroll
      for(int i=0;i<4;i++)
        acc[i][j] = __builtin_amdgcn_mfma_f32_16x16x32_bf16(af[i], bf, acc[i][j], 0,0,0);
    }
  };

  short *A0=At[0], *A1=At[1], *A2=At[2];
  short *B0=Bt[0], *B1=Bt[1], *B2=Bt[2];
  stage2(sA, kbeg,    A0, tid); stage2(sB, kbeg,    B0, tid);
  stage2(sA, kbeg+32, A1, tid); stage2(sB, kbeg+32, B1, tid);
  for(int s=0; s<9; s++){
    const int k2 = kbeg + (s+2)*32;
    stage2(sA, k2, A2, tid); stage2(sB, k2, B2, tid);
    asm volatile("s_waitcnt vmcnt(8)" ::: "memory");
    __builtin_amdgcn_s_barrier();
    __builtin_amdgcn_sched_barrier(0);
    kstep(A0, B0);
    __builtin_amdgcn_sched_barrier(0);
    __builtin_amdgcn_s_barrier();
    short* t;
    t=A0; A0=A1; A1=A2; A2=t;
    t=B0; B0=B1; B1=B2; B2=t;
  }
  asm volatile("s_waitcnt vmcnt(4)" ::: "memory");
  __builtin_amdgcn_s_barrier();
  __builtin_amdgcn_sched_barrier(0);
  kstep(A0, B0);
  __builtin_amdgcn_sched_barrier(0);
  __builtin_amdgcn_s_barrier();
  asm volatile("s_waitcnt vmcnt(0)" ::: "memory");
  __builtin_amdgcn_s_barrier();
  __builtin_amdgcn_sched_barrier(0);
  kstep(A1, B1);

  #pragma unroll
  for(int i=0;i<4;i++)
    #pragma unroll
    for(int j=0;j<4;j++){
      const int rbase = wm + i*16 + quad*4, col = wn + j*16 + fr;
      #pragma unroll
      for(int reg=0;reg<4;reg++)
        atomicAdd(&RD[((long)(t0+rbase+reg)*2 + slot)*128 + col], acc[i][j][reg]);
    }
}

// ---------------- K5b: RDhat[t][c] (f16) = alpha * RD at selected expert blocks ----------------
__global__ void k_scatter(const float* __restrict__ RD, const int* __restrict__ sel,
                          __half* __restrict__ RDhat){
  const int idx = blockIdx.x*256 + threadIdx.x;   // over T*128
  const int t = idx>>7, c = idx&127, e = c>>4;
  const int s0 = sel[t*2], s1 = sel[t*2+1];
  float v = 0.f;
  if(e == s0) v = LALPHA * RD[((long)t*2+0)*128 + c];
  else if(e == s1) v = LALPHA * RD[((long)t*2+1)*128 + c];
  RDhat[idx] = __float2half(v);
}

// ---------------- K6: out += chsum @ wdb^T (split-K=2, depth-2 pipeline) + RDhat @ wdbcat^T ----------------
__global__ __launch_bounds__(256,2) void k_down(
    const unsigned short* __restrict__ chsum, const short* __restrict__ wdb,
    const short* __restrict__ RDhat, const short* __restrict__ wdbcat,
    float* __restrict__ out){
  __shared__ __align__(16) short At[3][4096];
  __shared__ __align__(16) short Bt[3][4096];
  const int d0 = blockIdx.x*128, t0 = blockIdx.y*128, ks = blockIdx.z;
  const int tid = threadIdx.x, lane = tid&63, wave = tid>>6;
  const int wm=(wave>>1)*64, wn=(wave&1)*64, fr=lane&15, quad=lane>>4;
  f32x4 acc[4][4];
  #pragma unroll
  for(int i=0;i<4;i++)
    #pragma unroll
    for(int j=0;j<4;j++) acc[i][j]=(f32x4){0.f,0.f,0.f,0.f};
  const Src2 sA = mk_src((const short*)chsum + (long)t0*DHID, DHID, tid);
  const Src2 sB = mk_src(wdb + (long)d0*DHID, DHID, tid);
  const int kbeg = ks*2816;

  auto kstep = [&](const short* A, const short* B){
    s16x8 af[4];
    #pragma unroll
    for(int i=0;i<4;i++) af[i] = fragb(A, wm + i*16 + fr, quad);
    #pragma unroll
    for(int j=0;j<4;j++){
      const s16x8 bf = fragb(B, wn + j*16 + fr, quad);
      #pragma unroll
      for(int i=0;i<4;i++)
        acc[i][j] = __builtin_amdgcn_mfma_f32_16x16x32_bf16(af[i], bf, acc[i][j], 0,0,0);
    }
  };

  short *A0=At[0], *A1=At[1], *A2=At[2];
  short *B0=Bt[0], *B1=Bt[1], *B2=Bt[2];
  stage2(sA, kbeg,    A0, tid); stage2(sB, kbeg,    B0, tid);
  stage2(sA, kbeg+32, A1, tid); stage2(sB, kbeg+32, B1, tid);
  for(int s=0; s<86; s++){
    const int k2 = kbeg + (s+2)*32;
    stage2(sA, k2, A2, tid); stage2(sB, k2, B2, tid);
    asm volatile("s_waitcnt vmcnt(8)" ::: "memory");
    __builtin_amdgcn_s_barrier();
    __builtin_amdgcn_sched_barrier(0);
    kstep(A0, B0);
    __builtin_amdgcn_sched_barrier(0);
    __builtin_amdgcn_s_barrier();
    short* t;
    t=A0; A0=A1; A1=A2; A2=t;
    t=B0; B0=B1; B1=B2; B2=t;
  }
  asm volatile("s_waitcnt vmcnt(4)" ::: "memory");
  __builtin_amdgcn_s_barrier();
  __builtin_amdgcn_sched_barrier(0);
  kstep(A0, B0);
  __builtin_amdgcn_sched_barrier(0);
  __builtin_amdgcn_s_barrier();
  asm volatile("s_waitcnt vmcnt(0)" ::: "memory");
  __builtin_amdgcn_s_barrier();
  __builtin_amdgcn_sched_barrier(0);
  kstep(A1, B1);
  __builtin_amdgcn_s_barrier();

  if(ks == 0){
    const Src2 sAh = mk_src(RDhat + (long)t0*128, 128, tid);
    const Src2 sBh = mk_src(wdbcat + (long)d0*128, 128, tid);
    stage2(sAh, 0, At[0], tid); stage2(sBh, 0, Bt[0], tid);
    __syncthreads();
    int cur = 0;
    for(int k0=0; k0<128; k0+=32){
      const int nxt = cur^1;
      if(k0+32 < 128){
        stage2(sAh, k0+32, At[nxt], tid);
        stage2(sBh, k0+32, Bt[nxt], tid);
      }
      __builtin_amdgcn_sched_barrier(0);
      f16x8 af[4];
      #pragma unroll
      for(int i=0;i<4;i++) af[i] = fragh(At[cur], wm + i*16 + fr, quad);
      #pragma unroll
      for(int j=0;j<4;j++){
        const f16x8 bf = fragh(Bt[cur], wn + j*16 + fr, quad);
        #pragma unroll
        for(int i=0;i<4;i++)
          acc[i][j] = __builtin_amdgcn_mfma_f32_16x16x32_f16(af[i], bf, acc[i][j], 0,0,0);
      }
      __syncthreads();
      cur = nxt;
    }
  }
  #pragma unroll
  for(int i=0;i<4;i++)
    #pragma unroll
    for(int j=0;j<4;j++){
      const int rbase = wm + i*16 + quad*4, col = wn + j*16 + fr;
      #pragma unroll
      for(int reg=0;reg<4;reg++)
        atomicAdd(&out[(long)(t0+rbase+reg)*DMODEL + d0 + col], acc[i][j][reg]);
    }
}

extern "C" void kernel_launch(void* const* d_in, const int* in_sizes, int n_in,
                              void* d_out, int out_size, void* d_ws, size_t ws_size,
                              hipStream_t stream){
  (void)in_sizes; (void)n_in; (void)out_size; (void)ws_size;
  const float* x      = (const float*)d_in[0];
  const float* gate_w = (const float*)d_in[1];
  const float* w_up   = (const float*)d_in[2];
  const float* w_gate = (const float*)d_in[3];
  const float* w_down = (const float*)d_in[4];
  const float* up_A   = (const float*)d_in[5];
  const float* up_B   = (const float*)d_in[6];
  const float* gate_A = (const float*)d_in[7];
  const float* gate_B = (const float*)d_in[8];
  const float* down_A = (const float*)d_in[9];
  const float* down_B = (const float*)d_in[10];
  float* out = (float*)d_out;

  char* ws = (char*)d_ws;
  size_t off = 0;
  auto alloc = [&](size_t bytes){ void* p = ws + off; off += (bytes + 255) & ~(size_t)255; return p; };
  short* xb       = (short*)alloc((size_t)TOKENS*DMODEL*2);
  short* wub      = (short*)alloc((size_t)DHID*DMODEL*2);
  short* wgb      = (short*)alloc((size_t)DHID*DMODEL*2);
  short* wdb      = (short*)alloc((size_t)DMODEL*DHID*2);
  short* daA      = (short*)alloc((size_t)128*DHID*2);
  short* acat     = (short*)alloc((size_t)256*DMODEL*2);
  short* upBcat   = (short*)alloc((size_t)DHID*128*2);
  short* gateBcat = (short*)alloc((size_t)DHID*128*2);
  short* wdbcat   = (short*)alloc((size_t)DMODEL*128*2);
  unsigned short* ch    = (unsigned short*)alloc((size_t)2*TOKENS*DHID*2);
  unsigned short* chsum = (unsigned short*)alloc((size_t)TOKENS*DHID*2);
  short* LF     = (short*)alloc((size_t)704*65536*2);   // chunk-major fragment LoRA deltas
  float* Rall   = (float*)alloc((size_t)TOKENS*256*4);
  short* RselU  = (short*)alloc((size_t)2*TOKENS*128*2);
  short* RselG  = (short*)alloc((size_t)2*TOKENS*128*2);
  float* RD     = (float*)alloc((size_t)TOKENS*2*128*4);
  __half* RDhat = (__half*)alloc((size_t)TOKENS*128*2);
  int*   sel    = (int*)alloc((size_t)TOKENS*2*4);
  float* topv   = (float*)alloc((size_t)TOKENS*2*4);
  float* cw     = (float*)alloc((size_t)TOKENS*2*4);

  (void)hipMemsetAsync(RD, 0, (size_t)TOKENS*2*128*4, stream);
  (void)hipMemsetAsync(Rall, 0, (size_t)TOKENS*256*4, stream);
  (void)hipMemsetAsync(out, 0, (size_t)TOKENS*DMODEL*4, stream);
  k_cast<<<40768, 256, 0, stream>>>(x, w_up, w_gate, w_down, up_A, gate_A, down_A,
                                    up_B, gate_B, down_B,
                                    xb, wub, wgb, wdb, daA, acat, upBcat, gateBcat, wdbcat);
  k_router<<<512, 256, 0, stream>>>(x, gate_w, sel, topv);
  k_softmax<<<4, 256, 0, stream>>>(topv, cw);
  k_rank<<<dim3(2,16,8), 256, 0, stream>>>(xb, acat, Rall);
  k_rsel<<<2048, 256, 0, stream>>>(Rall, sel, RselU, RselG);
  k_lora<<<dim3(44,16,2), 256, 0, stream>>>(RselU, RselG, upBcat, gateBcat, LF);
  k_main<<<dim3(44,8), 512, 0, stream>>>(xb, wub, wgb, LF, cw, ch, chsum);
  k_rd<<<dim3(32,16), 256, 0, stream>>>(ch, daA, RD);
  k_scatter<<<1024, 256, 0, stream>>>(RD, sel, RDhat);
  k_down<<<dim3(16,16,2), 256, 0, stream>>>(chsum, wdb, (const short*)RDhat, wdbcat, out);
}